// Round 7
// baseline (1199.507 us; speedup 1.0000x reference)
//
#include <hip/hip_runtime.h>
#include <math.h>

#define NN 40000
#define NE 640000
#define KIN 776
#define HH 128
#define NCLS 5

typedef __attribute__((ext_vector_type(8))) short bf16x8;
typedef __attribute__((ext_vector_type(4))) short bf16x4;
typedef __attribute__((ext_vector_type(4))) float f32x4;

__device__ __forceinline__ float bf2f(short u) {
    return __uint_as_float(((unsigned)(unsigned short)u) << 16);
}
__device__ __forceinline__ short f2bf(float f) {          // RNE
    unsigned u = __float_as_uint(f);
    u += 0x7fffu + ((u >> 16) & 1u);
    return (short)(u >> 16);
}

// MFMA GEMM (encoder): C[M,128] = f32A[M,K] @ W[K,128] + bias -> bf16.
template<int NSTEP, bool TAIL8>
__global__ __launch_bounds__(256)
void mfma_gemm(const float* __restrict__ Af, const short* __restrict__ Wp,
               const float* __restrict__ bias, short* __restrict__ Cb, int K)
{
    const int lane = threadIdx.x & 63;
    const int wave = threadIdx.x >> 6;
    const int q = lane >> 4;
    const int c16 = lane & 15;
    const int row = blockIdx.x * 64 + wave * 16 + c16;

    f32x4 acc[8];
#pragma unroll
    for (int n = 0; n < 8; ++n) acc[n] = (f32x4){0.f, 0.f, 0.f, 0.f};

    for (int kt = 0; kt < NSTEP; ++kt) {
        bf16x8 afrag;
        const int kbase = kt * 32 + q * 8;
        if (!TAIL8 || kt < NSTEP - 1 || q == 0) {
            const float* p = Af + (size_t)row * K + kbase;
            const float4 x = *(const float4*)p;
            const float4 y = *(const float4*)(p + 4);
            afrag[0] = f2bf(x.x); afrag[1] = f2bf(x.y);
            afrag[2] = f2bf(x.z); afrag[3] = f2bf(x.w);
            afrag[4] = f2bf(y.x); afrag[5] = f2bf(y.y);
            afrag[6] = f2bf(y.z); afrag[7] = f2bf(y.w);
        } else {
#pragma unroll
            for (int j = 0; j < 8; ++j) afrag[j] = 0;
        }
        const int kb = kt * 4 + q;
#pragma unroll
        for (int n = 0; n < 8; ++n) {
            const bf16x8 wfrag =
                *(const bf16x8*)(Wp + (size_t)kb * 1024 + (n * 16 + c16) * 8);
            acc[n] = __builtin_amdgcn_mfma_f32_16x16x32_bf16(wfrag, afrag, acc[n], 0, 0, 0);
        }
    }
#pragma unroll
    for (int n = 0; n < 8; ++n) {
        const int col = n * 16 + q * 4;
        const float4 b4 = *(const float4*)(bias + col);
        bf16x4 o;
        o[0] = f2bf(acc[n][0] + b4.x); o[1] = f2bf(acc[n][1] + b4.y);
        o[2] = f2bf(acc[n][2] + b4.z); o[3] = f2bf(acc[n][3] + b4.w);
        *(bf16x4*)(Cb + (size_t)row * HH + col) = o;
    }
}

// Fused 4 node linears: one A-fragment load feeds 4 weight matrices.
// ABN=false: A = h0 (bf16). ABN=true: A = relu(bn(hnew f32)).
template<bool ABN>
__global__ __launch_bounds__(256, 2)
void fused4_k(const short* __restrict__ hb, const float* __restrict__ hf,
              const float* __restrict__ bnp,
              const short* __restrict__ w0, const short* __restrict__ w1,
              const short* __restrict__ w2, const short* __restrict__ w3,
              const float* __restrict__ b0, const float* __restrict__ b1,
              const float* __restrict__ b2, const float* __restrict__ b3,
              float* __restrict__ Ah, short* __restrict__ Bh,
              short* __restrict__ Dh, short* __restrict__ Eh)
{
    const int lane = threadIdx.x & 63;
    const int wave = threadIdx.x >> 6;
    const int q = lane >> 4;
    const int c16 = lane & 15;
    const int row = blockIdx.x * 64 + wave * 16 + c16;

    f32x4 acc[4][8];
#pragma unroll
    for (int t = 0; t < 4; ++t)
#pragma unroll
        for (int n = 0; n < 8; ++n) acc[t][n] = (f32x4){0.f, 0.f, 0.f, 0.f};

    const short* const ws[4] = {w0, w1, w2, w3};
#pragma unroll
    for (int kt = 0; kt < 4; ++kt) {
        const int kbase = kt * 32 + q * 8;
        bf16x8 afrag;
        if (!ABN) {
            afrag = *(const bf16x8*)(hb + (size_t)row * HH + kbase);
        } else {
            const float* p = hf + (size_t)row * HH + kbase;
            const float4 x = *(const float4*)p;
            const float4 y = *(const float4*)(p + 4);
            const float4 s0 = *(const float4*)(bnp + kbase);
            const float4 s1 = *(const float4*)(bnp + kbase + 4);
            const float4 t0 = *(const float4*)(bnp + HH + kbase);
            const float4 t1 = *(const float4*)(bnp + HH + kbase + 4);
            const float xv[8] = {x.x, x.y, x.z, x.w, y.x, y.y, y.z, y.w};
            const float scv[8] = {s0.x, s0.y, s0.z, s0.w, s1.x, s1.y, s1.z, s1.w};
            const float shv[8] = {t0.x, t0.y, t0.z, t0.w, t1.x, t1.y, t1.z, t1.w};
#pragma unroll
            for (int j = 0; j < 8; ++j)
                afrag[j] = f2bf(fmaxf(fmaf(xv[j], scv[j], shv[j]), 0.f));
        }
        const int kb = kt * 4 + q;
#pragma unroll
        for (int t = 0; t < 4; ++t)
#pragma unroll
            for (int n = 0; n < 8; ++n) {
                const bf16x8 wfrag =
                    *(const bf16x8*)(ws[t] + (size_t)kb * 1024 + (n * 16 + c16) * 8);
                acc[t][n] = __builtin_amdgcn_mfma_f32_16x16x32_bf16(wfrag, afrag, acc[t][n], 0, 0, 0);
            }
    }

    const float* const bs[4] = {b0, b1, b2, b3};
#pragma unroll
    for (int t = 0; t < 4; ++t) {
#pragma unroll
        for (int n = 0; n < 8; ++n) {
            const int col = n * 16 + q * 4;
            const float4 b4 = *(const float4*)(bs[t] + col);
            const float v[4] = {acc[t][n][0] + b4.x, acc[t][n][1] + b4.y,
                                acc[t][n][2] + b4.z, acc[t][n][3] + b4.w};
            if (t == 0) {
                *(float4*)(Ah + (size_t)row * HH + col) = make_float4(v[0], v[1], v[2], v[3]);
            } else {
                bf16x4 o;
#pragma unroll
                for (int j = 0; j < 4; ++j) o[j] = f2bf(v[j]);
                short* dstp = (t == 1) ? Bh : ((t == 2) ? Dh : Eh);
                *(bf16x4*)(dstp + (size_t)row * HH + col) = o;
            }
        }
    }
}

// ---- Layer-1 fused: e_new1 + enew store + e-stats + sigmoid seg-sum -> hnew.
// Wave = 8 sequential nodes; slot = lane>>4 (4 edge slots), cg = lane&15
// (8 cols, bf16x8). Eh[dst]=Eh[n] hoisted (dst uniform over node span).
__global__ __launch_bounds__(256)
void edge1seg_k(const float* __restrict__ ef, const int* __restrict__ eidx,
                const int* __restrict__ src_s, const int* __restrict__ rowptr,
                const float* __restrict__ G,
                const short* __restrict__ Dh, const short* __restrict__ Eh,
                const short* __restrict__ Bh, const float* __restrict__ Ah,
                short* __restrict__ enew, float* __restrict__ hnew,
                float* __restrict__ pbuf)
{
    const int wv = threadIdx.x >> 6;
    const int lane = threadIdx.x & 63;
    const int slot = lane >> 4;
    const int cg = lane & 15;
    const int col = cg * 8;
    const int n0 = (blockIdx.x * 4 + wv) * 8;

    const float4 g00 = *(const float4*)(G + col);
    const float4 g01 = *(const float4*)(G + col + 4);
    const float4 g10 = *(const float4*)(G + HH + col);
    const float4 g11 = *(const float4*)(G + HH + col + 4);
    const float4 gb0 = *(const float4*)(G + 2 * HH + col);
    const float4 gb1 = *(const float4*)(G + 2 * HH + col + 4);
    const float G0v[8] = {g00.x, g00.y, g00.z, g00.w, g01.x, g01.y, g01.z, g01.w};
    const float G1v[8] = {g10.x, g10.y, g10.z, g10.w, g11.x, g11.y, g11.z, g11.w};
    const float GBv[8] = {gb0.x, gb0.y, gb0.z, gb0.w, gb1.x, gb1.y, gb1.z, gb1.w};

    float esa[8] = {}, esq[8] = {};

    for (int nn = 0; nn < 8; ++nn) {
        const int n = n0 + nn;
        const int k0 = rowptr[n], k1 = rowptr[n + 1];
        const bf16x8 ehn = *(const bf16x8*)(Eh + (size_t)n * HH + col);
        float ehv[8];
#pragma unroll
        for (int j = 0; j < 8; ++j) ehv[j] = bf2f(ehn[j]);
        float num[8] = {}, den[8] = {};
        for (int k = k0 + slot; k < k1; k += 4) {
            const int e = eidx[k];
            const int s = src_s[k];
            const float f0 = ef[(size_t)e * 2];
            const float f1 = ef[(size_t)e * 2 + 1];
            const bf16x8 dh = *(const bf16x8*)(Dh + (size_t)s * HH + col);
            const bf16x8 bh = *(const bf16x8*)(Bh + (size_t)s * HH + col);
            bf16x8 o;
#pragma unroll
            for (int j = 0; j < 8; ++j) {
                const float v = fmaf(f0, G0v[j], fmaf(f1, G1v[j], GBv[j]))
                                + bf2f(dh[j]) + ehv[j];
                o[j] = f2bf(v);
                esa[j] += v; esq[j] += v * v;
                const float sg = 1.f / (1.f + __expf(-v));
                den[j] += sg;
                num[j] = fmaf(sg, bf2f(bh[j]), num[j]);
            }
            *(bf16x8*)(enew + (size_t)k * HH + col) = o;
        }
#pragma unroll
        for (int j = 0; j < 8; ++j) {
            num[j] += __shfl_xor(num[j], 16, 64);
            den[j] += __shfl_xor(den[j], 16, 64);
            num[j] += __shfl_xor(num[j], 32, 64);
            den[j] += __shfl_xor(den[j], 32, 64);
        }
        if (slot == 0) {
            const size_t idx = (size_t)n * HH + col;
            const float4 a0 = *(const float4*)(Ah + idx);
            const float4 a1 = *(const float4*)(Ah + idx + 4);
            const float av[8] = {a0.x, a0.y, a0.z, a0.w, a1.x, a1.y, a1.z, a1.w};
            float x[8];
#pragma unroll
            for (int j = 0; j < 8; ++j) x[j] = av[j] + num[j] / (den[j] + 1e-6f);
            *(float4*)(hnew + idx) = make_float4(x[0], x[1], x[2], x[3]);
            *(float4*)(hnew + idx + 4) = make_float4(x[4], x[5], x[6], x[7]);
        }
    }

    // e-BN stats: block LDS reduce (16 groups of lanes share cg), then atomics.
    __shared__ float sred[16][136];
    const int er = threadIdx.x >> 4;
    const int slotp = (blockIdx.x & 63) * 256;
#pragma unroll
    for (int j = 0; j < 8; ++j) sred[er][col + j] = esa[j];
    __syncthreads();
    for (int s2 = 8; s2 > 0; s2 >>= 1) {
        if (er < s2)
#pragma unroll
            for (int j = 0; j < 8; ++j) sred[er][col + j] += sred[er + s2][col + j];
        __syncthreads();
    }
    if (er == 0)
#pragma unroll
        for (int j = 0; j < 8; ++j) atomicAdd(pbuf + slotp + col + j, sred[0][col + j]);
    __syncthreads();
#pragma unroll
    for (int j = 0; j < 8; ++j) sred[er][col + j] = esq[j];
    __syncthreads();
    for (int s2 = 8; s2 > 0; s2 >>= 1) {
        if (er < s2)
#pragma unroll
            for (int j = 0; j < 8; ++j) sred[er][col + j] += sred[er + s2][col + j];
        __syncthreads();
    }
    if (er == 0)
#pragma unroll
        for (int j = 0; j < 8; ++j) atomicAdd(pbuf + slotp + 128 + col + j, sred[0][col + j]);
}

// ---- Layer-2 fused: e_new2 via MFMA (16 edges = B-columns per chunk),
// sigmoid + Bh[src]-weighted seg-sum in registers -> hnew. e_new2 NEVER stored.
// Wave = 8 sequential nodes; within chunk lane's edge = c16, cols = n8*16+q*4+j.
__global__ __launch_bounds__(256)
void edge2seg_k(const short* __restrict__ enew, const short* __restrict__ Wp,
                const float* __restrict__ bias, const float* __restrict__ bnp,
                const short* __restrict__ Dh, const short* __restrict__ Eh,
                const short* __restrict__ Bh, const int* __restrict__ src_s,
                const int* __restrict__ rowptr, const float* __restrict__ Ah,
                float* __restrict__ hnew)
{
    const int wv = threadIdx.x >> 6;
    const int lane = threadIdx.x & 63;
    const int q = lane >> 4;
    const int c16 = lane & 15;
    const int n0 = (blockIdx.x * 4 + wv) * 8;

    for (int nn = 0; nn < 8; ++nn) {
        const int n = n0 + nn;
        const int k0 = rowptr[n], k1 = rowptr[n + 1];
        float num[8][4] = {}, den[8][4] = {};
        const int nch = (k1 - k0 + 15) >> 4;
        for (int ch = 0; ch < nch; ++ch) {
            const int k = k0 + ch * 16 + c16;
            const bool valid = (k < k1);
            const int kr = valid ? k : k0;
            const int s = src_s[kr];

            // acc init = bias + Dh[src] + Eh[n]  (per-edge gathers hide under MFMA)
            f32x4 acc[8];
#pragma unroll
            for (int n8 = 0; n8 < 8; ++n8) {
                const int col = n8 * 16 + q * 4;
                const float4 b4 = *(const float4*)(bias + col);
                const bf16x4 dh = *(const bf16x4*)(Dh + (size_t)s * HH + col);
                const bf16x4 eh = *(const bf16x4*)(Eh + (size_t)n * HH + col);
                const float bb[4] = {b4.x, b4.y, b4.z, b4.w};
#pragma unroll
                for (int j = 0; j < 4; ++j)
                    acc[n8][j] = bb[j] + bf2f(dh[j]) + bf2f(eh[j]);
            }

#pragma unroll
            for (int kt = 0; kt < 4; ++kt) {
                const int kbase = kt * 32 + q * 8;
                const float4 sc0 = *(const float4*)(bnp + kbase);
                const float4 sc1 = *(const float4*)(bnp + kbase + 4);
                const float4 sh0 = *(const float4*)(bnp + HH + kbase);
                const float4 sh1 = *(const float4*)(bnp + HH + kbase + 4);
                const float scv[8] = {sc0.x, sc0.y, sc0.z, sc0.w, sc1.x, sc1.y, sc1.z, sc1.w};
                const float shv[8] = {sh0.x, sh0.y, sh0.z, sh0.w, sh1.x, sh1.y, sh1.z, sh1.w};
                const bf16x8 raw = *(const bf16x8*)(enew + (size_t)kr * HH + kbase);
                bf16x8 afrag;
#pragma unroll
                for (int j = 0; j < 8; ++j)
                    afrag[j] = f2bf(fmaxf(fmaf(bf2f(raw[j]), scv[j], shv[j]), 0.f));
                const int kb = kt * 4 + q;
#pragma unroll
                for (int n8 = 0; n8 < 8; ++n8) {
                    const bf16x8 wfrag =
                        *(const bf16x8*)(Wp + (size_t)kb * 1024 + (n8 * 16 + c16) * 8);
                    acc[n8] = __builtin_amdgcn_mfma_f32_16x16x32_bf16(wfrag, afrag, acc[n8], 0, 0, 0);
                }
            }

            // sigmoid + weight by Bh[src]; pad lanes excluded.
#pragma unroll
            for (int n8 = 0; n8 < 8; ++n8) {
                const int col = n8 * 16 + q * 4;
                const bf16x4 bh = *(const bf16x4*)(Bh + (size_t)s * HH + col);
                if (valid) {
#pragma unroll
                    for (int j = 0; j < 4; ++j) {
                        const float sg = 1.f / (1.f + __expf(-acc[n8][j]));
                        den[n8][j] += sg;
                        num[n8][j] = fmaf(sg, bf2f(bh[j]), num[n8][j]);
                    }
                }
            }
        }

        // reduce over the 16 edge-lanes (c16)
#pragma unroll
        for (int n8 = 0; n8 < 8; ++n8)
#pragma unroll
            for (int j = 0; j < 4; ++j) {
                float nv = num[n8][j], dv = den[n8][j];
                nv += __shfl_xor(nv, 1, 64);  dv += __shfl_xor(dv, 1, 64);
                nv += __shfl_xor(nv, 2, 64);  dv += __shfl_xor(dv, 2, 64);
                nv += __shfl_xor(nv, 4, 64);  dv += __shfl_xor(dv, 4, 64);
                nv += __shfl_xor(nv, 8, 64);  dv += __shfl_xor(dv, 8, 64);
                num[n8][j] = nv; den[n8][j] = dv;
            }
        if (c16 == 0) {
#pragma unroll
            for (int n8 = 0; n8 < 8; ++n8) {
                const int col = n8 * 16 + q * 4;
                const size_t idx = (size_t)n * HH + col;
                const float4 a4 = *(const float4*)(Ah + idx);
                const float av[4] = {a4.x, a4.y, a4.z, a4.w};
                float x[4];
#pragma unroll
                for (int j = 0; j < 4; ++j)
                    x[j] = av[j] + num[n8][j] / (den[n8][j] + 1e-6f);
                *(float4*)(hnew + idx) = make_float4(x[0], x[1], x[2], x[3]);
            }
        }
    }
}

// Fused readout: logits = relu(relu(bn(hnew)) @ w1 + b1) @ w2 + b2 — z in regs.
__global__ __launch_bounds__(256)
void readout_k(const float* __restrict__ hnew, const float* __restrict__ bnp,
               const short* __restrict__ Wp, const float* __restrict__ b1,
               const float* __restrict__ w2, const float* __restrict__ b2,
               float* __restrict__ out)
{
    const int lane = threadIdx.x & 63;
    const int wave = threadIdx.x >> 6;
    const int q = lane >> 4;
    const int c16 = lane & 15;
    const int row = blockIdx.x * 64 + wave * 16 + c16;

    f32x4 acc[8];
#pragma unroll
    for (int n = 0; n < 8; ++n) acc[n] = (f32x4){0.f, 0.f, 0.f, 0.f};

#pragma unroll
    for (int kt = 0; kt < 4; ++kt) {
        const int kbase = kt * 32 + q * 8;
        const float* p = hnew + (size_t)row * HH + kbase;
        const float4 x = *(const float4*)p;
        const float4 y = *(const float4*)(p + 4);
        const float4 s0 = *(const float4*)(bnp + kbase);
        const float4 s1 = *(const float4*)(bnp + kbase + 4);
        const float4 t0 = *(const float4*)(bnp + HH + kbase);
        const float4 t1 = *(const float4*)(bnp + HH + kbase + 4);
        const float xv[8] = {x.x, x.y, x.z, x.w, y.x, y.y, y.z, y.w};
        const float scv[8] = {s0.x, s0.y, s0.z, s0.w, s1.x, s1.y, s1.z, s1.w};
        const float shv[8] = {t0.x, t0.y, t0.z, t0.w, t1.x, t1.y, t1.z, t1.w};
        bf16x8 afrag;
#pragma unroll
        for (int j = 0; j < 8; ++j)
            afrag[j] = f2bf(fmaxf(fmaf(xv[j], scv[j], shv[j]), 0.f));
        const int kb = kt * 4 + q;
#pragma unroll
        for (int n = 0; n < 8; ++n) {
            const bf16x8 wfrag =
                *(const bf16x8*)(Wp + (size_t)kb * 1024 + (n * 16 + c16) * 8);
            acc[n] = __builtin_amdgcn_mfma_f32_16x16x32_bf16(wfrag, afrag, acc[n], 0, 0, 0);
        }
    }

    float part[NCLS] = {};
#pragma unroll
    for (int n = 0; n < 8; ++n) {
        const int col = n * 16 + q * 4;
        const float4 b4 = *(const float4*)(b1 + col);
        const float bb[4] = {b4.x, b4.y, b4.z, b4.w};
#pragma unroll
        for (int j = 0; j < 4; ++j) {
            const float zv = fmaxf(acc[n][j] + bb[j], 0.f);
#pragma unroll
            for (int t = 0; t < NCLS; ++t)
                part[t] = fmaf(zv, w2[(col + j) * NCLS + t], part[t]);
        }
    }
#pragma unroll
    for (int t = 0; t < NCLS; ++t) {
        part[t] += __shfl_xor(part[t], 16, 64);
        part[t] += __shfl_xor(part[t], 32, 64);
    }
    if (q == 0) {
#pragma unroll
        for (int t = 0; t < NCLS; ++t)
            out[(size_t)row * NCLS + t] = part[t] + b2[t];
    }
}

// Pack all weight matrices to bf16 fragments: Wp[kb][col][8] = W[kb*8+j][col].
__global__ __launch_bounds__(256)
void prepack_k(const float* __restrict__ enc_nw, const float* __restrict__ lin_w,
               const float* __restrict__ mlp_w1, short* __restrict__ wp)
{
    const int t = blockIdx.x * 256 + threadIdx.x;
    if (t >= 260 * 128) return;
    const int kbg = t >> 7, col = t & 127;
    const int kb0[11]  = {0, 100, 116, 132, 148, 164, 180, 196, 212, 228, 244};
    const int psel[11] = {0, 1, 1, 1, 1, 1, 1, 1, 1, 1, 2};
    const int soff[11] = {0, 0 * 16384, 1 * 16384, 3 * 16384, 4 * 16384,
                          5 * 16384, 6 * 16384, 7 * 16384, 8 * 16384, 9 * 16384, 0};
    const int Ksrc[11] = {KIN, 128, 128, 128, 128, 128, 128, 128, 128, 128, 128};
    int e = 10;
    while (e > 0 && kbg < kb0[e]) --e;
    const float* base = (psel[e] == 0) ? enc_nw : ((psel[e] == 1) ? lin_w : mlp_w1);
    const int kbl = kbg - kb0[e];
    bf16x8 o;
#pragma unroll
    for (int j = 0; j < 8; ++j) {
        const int k = kbl * 8 + j;
        const float v = (k < Ksrc[e]) ? base[(size_t)soff[e] + (size_t)k * HH + col] : 0.f;
        o[j] = f2bf(v);
    }
    *(bf16x8*)(wp + (size_t)kbg * 1024 + col * 8) = o;
}

// Rank-2 collapse of layer-1 edge GEMM.
__global__ void gpre_k(const float* __restrict__ enc_ew, const float* __restrict__ enc_eb,
                       const float* __restrict__ Wc, const float* __restrict__ bc,
                       float* __restrict__ G)
{
    const int c = threadIdx.x;
    float a0 = 0.f, a1 = 0.f, ab = 0.f;
    for (int k = 0; k < HH; ++k) {
        const float w = Wc[k * HH + c];
        a0 = fmaf(enc_ew[k], w, a0);
        a1 = fmaf(enc_ew[HH + k], w, a1);
        ab = fmaf(enc_eb[k], w, ab);
    }
    G[c] = a0; G[HH + c] = a1; G[2 * HH + c] = ab + bc[c];
}

// ---- CSR build ----
__global__ __launch_bounds__(256)
void hist_k(const int* __restrict__ dst, int* __restrict__ cnt)
{
    const int e = blockIdx.x * 256 + threadIdx.x;
    if (e < NE) atomicAdd(cnt + dst[e], 1);
}

__global__ __launch_bounds__(1024)
void scan_k(const int* __restrict__ cnt, int* __restrict__ rowptr, int* __restrict__ wr)
{
    __shared__ int s[1024];
    const int t = threadIdx.x;
    const int base = t * 40;
    int sum = 0;
    for (int i = 0; i < 40; ++i) {
        const int idx = base + i;
        if (idx < NN) sum += cnt[idx];
    }
    s[t] = sum;
    __syncthreads();
    for (int off = 1; off < 1024; off <<= 1) {
        const int v = (t >= off) ? s[t - off] : 0;
        __syncthreads();
        s[t] += v;
        __syncthreads();
    }
    int run = (t == 0) ? 0 : s[t - 1];
    for (int i = 0; i < 40; ++i) {
        const int idx = base + i;
        if (idx < NN) {
            rowptr[idx] = run;
            wr[idx] = run;
            run += cnt[idx];
        }
    }
    if (t == 1023) rowptr[NN] = s[1023];
}

__global__ __launch_bounds__(256)
void scatter_k(const int* __restrict__ dst, const int* __restrict__ src,
               int* __restrict__ wr, int* __restrict__ eidx,
               int* __restrict__ src_s)
{
    const int e = blockIdx.x * 256 + threadIdx.x;
    if (e < NE) {
        const int d = dst[e];
        const int p = atomicAdd(wr + d, 1);
        eidx[p] = e;
        src_s[p] = src[e];
    }
}

// h-BN column stats -> pbuf partials.
__global__ __launch_bounds__(256)
void hstats_k(const float* __restrict__ hnew, float* __restrict__ pbuf)
{
    const int tid = threadIdx.x;
    const int c = tid & 127, sub = tid >> 7;
    const int r0 = blockIdx.x * 256;
    float sa = 0.f, qa = 0.f;
    for (int i = sub; i < 256; i += 2) {
        const int r = r0 + i;
        if (r >= NN) break;
        const float x = hnew[(size_t)r * HH + c];
        sa += x; qa += x * x;
    }
    __shared__ float red[256];
    red[tid] = sa; __syncthreads();
    if (tid < 128) atomicAdd(pbuf + (blockIdx.x & 63) * 256 + c, red[tid] + red[tid + 128]);
    __syncthreads();
    red[tid] = qa; __syncthreads();
    if (tid < 128) atomicAdd(pbuf + (blockIdx.x & 63) * 256 + 128 + c, red[tid] + red[tid + 128]);
}

// BN params from 64-slot partials.
__global__ void make_bnp2(const float* __restrict__ pbuf, const float* __restrict__ g,
                          const float* __restrict__ b, float cntInv,
                          float* __restrict__ out)
{
    const int c = threadIdx.x;
    float s = 0.f, q = 0.f;
    for (int i = 0; i < 64; ++i) {
        s += pbuf[i * 256 + c];
        q += pbuf[i * 256 + 128 + c];
    }
    const float m = s * cntInv;
    const float var = q * cntInv - m * m;
    const float rs = rsqrtf(var + 1e-5f);
    const float sc = g[c] * rs;
    out[c] = sc;
    out[128 + c] = b[c] - m * sc;
}

extern "C" void kernel_launch(void* const* d_in, const int* in_sizes, int n_in,
                              void* d_out, int out_size, void* d_ws, size_t ws_size,
                              hipStream_t stream)
{
    const float* node_feat = (const float*)d_in[0];
    const float* edge_feat = (const float*)d_in[1];
    const int*   src       = (const int*)d_in[2];
    const int*   dst       = (const int*)d_in[3];
    const float* enc_nw    = (const float*)d_in[4];
    const float* enc_nb    = (const float*)d_in[5];
    const float* enc_ew    = (const float*)d_in[6];
    const float* enc_eb    = (const float*)d_in[7];
    const float* lin_w     = (const float*)d_in[8];
    const float* lin_b     = (const float*)d_in[9];
    const float* bnh_g     = (const float*)d_in[10];
    const float* bnh_b     = (const float*)d_in[11];
    const float* bne_g     = (const float*)d_in[12];
    const float* bne_b     = (const float*)d_in[13];
    const float* mlp_w1    = (const float*)d_in[14];
    const float* mlp_b1    = (const float*)d_in[15];
    const float* mlp_w2    = (const float*)d_in[16];
    const float* mlp_b2    = (const float*)d_in[17];
    float* out = (float*)d_out;

    char* base = (char*)d_ws;
    size_t off = 0;
    auto alloc = [&](size_t bytes) -> void* {
        void* p = base + off;
        off = (off + bytes + 255) & ~(size_t)255;
        return p;
    };
    const size_t NH = (size_t)NN * HH;
    float* hnew  = (float*)alloc(NH * 4);
    float* Ah    = (float*)alloc(NH * 4);
    short* h0    = (short*)alloc(NH * 2);
    short* Bh    = (short*)alloc(NH * 2);
    short* Dh    = (short*)alloc(NH * 2);
    short* Eh    = (short*)alloc(NH * 2);
    short* enew  = (short*)alloc((size_t)NE * HH * 2);
    short* wpack = (short*)alloc((size_t)260 * 1024 * 2);
    float* G     = (float*)alloc(384 * 4);
    float* bnpe  = (float*)alloc(256 * 4);
    float* bnph  = (float*)alloc(256 * 4);
    float* pbe   = (float*)alloc(16384 * 4);
    float* pbh0  = (float*)alloc(16384 * 4);
    float* pbh1  = (float*)alloc(16384 * 4);
    int* cnt     = (int*)alloc(NN * 4);
    int* rowptr  = (int*)alloc((NN + 1) * 4);
    int* wr      = (int*)alloc(NN * 4);
    int* eidx    = (int*)alloc((size_t)NE * 4);
    int* src_s   = (int*)alloc((size_t)NE * 4);

    const dim3 blk(256);

    hipMemsetAsync(cnt, 0, NN * 4, stream);
    hipMemsetAsync(pbe, 0, 3 * 16384 * 4, stream);   // pbe,pbh0,pbh1 contiguous
    hist_k<<<2500, blk, 0, stream>>>(dst, cnt);
    scan_k<<<1, 1024, 0, stream>>>(cnt, rowptr, wr);
    scatter_k<<<2500, blk, 0, stream>>>(dst, src, wr, eidx, src_s);
    prepack_k<<<130, blk, 0, stream>>>(enc_nw, lin_w, mlp_w1, wpack);
    gpre_k<<<1, 128, 0, stream>>>(enc_ew, enc_eb, lin_w + 2 * 16384, lin_b + 2 * HH, G);

    // encoder: h0 = bf16(node_feat @ enc_nw + enc_nb)
    mfma_gemm<25, true><<<625, blk, 0, stream>>>(node_feat, wpack, enc_nb, h0, KIN);

    // ---- layer 0 ----
    {
        const float* Bv = lin_b;
        fused4_k<false><<<625, blk, 0, stream>>>(
            h0, nullptr, nullptr,
            wpack + (size_t)100 * 1024, wpack + (size_t)116 * 1024,
            wpack + (size_t)132 * 1024, wpack + (size_t)148 * 1024,
            Bv + 0 * HH, Bv + 1 * HH, Bv + 3 * HH, Bv + 4 * HH,
            Ah, Bh, Dh, Eh);
        edge1seg_k<<<1250, blk, 0, stream>>>(edge_feat, eidx, src_s, rowptr, G,
                                             Dh, Eh, Bh, Ah, enew, hnew, pbe);
        make_bnp2<<<1, 128, 0, stream>>>(pbe, bne_g, bne_b, 1.f / NE, bnpe);
        hstats_k<<<157, blk, 0, stream>>>(hnew, pbh0);
        make_bnp2<<<1, 128, 0, stream>>>(pbh0, bnh_g, bnh_b, 1.f / NN, bnph);
    }

    // ---- layer 1 ----
    {
        const float* Bv = lin_b + 5 * HH;
        fused4_k<true><<<625, blk, 0, stream>>>(
            nullptr, hnew, bnph,
            wpack + (size_t)164 * 1024, wpack + (size_t)180 * 1024,
            wpack + (size_t)212 * 1024, wpack + (size_t)228 * 1024,
            Bv + 0 * HH, Bv + 1 * HH, Bv + 3 * HH, Bv + 4 * HH,
            Ah, Bh, Dh, Eh);
        edge2seg_k<<<1250, blk, 0, stream>>>(enew, wpack + (size_t)196 * 1024,
                                             Bv + 2 * HH, bnpe, Dh, Eh, Bh,
                                             src_s, rowptr, Ah, hnew);
        hstats_k<<<157, blk, 0, stream>>>(hnew, pbh1);
        make_bnp2<<<1, 128, 0, stream>>>(pbh1, bnh_g + HH, bnh_b + HH, 1.f / NN, bnph);
    }

    // fused readout
    readout_k<<<625, blk, 0, stream>>>(hnew, bnph, wpack + (size_t)244 * 1024,
                                       mlp_b1, mlp_w2, mlp_b2, out);
}

// Round 8
// 854.726 us; speedup vs baseline: 1.4034x; 1.4034x over previous
//
#include <hip/hip_runtime.h>
#include <math.h>

#define NN 40000
#define NE 640000
#define KIN 776
#define HH 128
#define NCLS 5

typedef __attribute__((ext_vector_type(8))) short bf16x8;
typedef __attribute__((ext_vector_type(4))) short bf16x4;
typedef __attribute__((ext_vector_type(4))) float f32x4;

__device__ __forceinline__ float bf2f(short u) {
    return __uint_as_float(((unsigned)(unsigned short)u) << 16);
}
__device__ __forceinline__ short f2bf(float f) {          // RNE
    unsigned u = __float_as_uint(f);
    u += 0x7fffu + ((u >> 16) & 1u);
    return (short)(u >> 16);
}

// MFMA GEMM (encoder): C[M,128] = f32A[M,K] @ W[K,128] + bias -> bf16.
template<int NSTEP, bool TAIL8>
__global__ __launch_bounds__(256)
void mfma_gemm(const float* __restrict__ Af, const short* __restrict__ Wp,
               const float* __restrict__ bias, short* __restrict__ Cb, int K)
{
    const int lane = threadIdx.x & 63;
    const int wave = threadIdx.x >> 6;
    const int q = lane >> 4;
    const int c16 = lane & 15;
    const int row = blockIdx.x * 64 + wave * 16 + c16;

    f32x4 acc[8];
#pragma unroll
    for (int n = 0; n < 8; ++n) acc[n] = (f32x4){0.f, 0.f, 0.f, 0.f};

    for (int kt = 0; kt < NSTEP; ++kt) {
        bf16x8 afrag;
        const int kbase = kt * 32 + q * 8;
        if (!TAIL8 || kt < NSTEP - 1 || q == 0) {
            const float* p = Af + (size_t)row * K + kbase;
            const float4 x = *(const float4*)p;
            const float4 y = *(const float4*)(p + 4);
            afrag[0] = f2bf(x.x); afrag[1] = f2bf(x.y);
            afrag[2] = f2bf(x.z); afrag[3] = f2bf(x.w);
            afrag[4] = f2bf(y.x); afrag[5] = f2bf(y.y);
            afrag[6] = f2bf(y.z); afrag[7] = f2bf(y.w);
        } else {
#pragma unroll
            for (int j = 0; j < 8; ++j) afrag[j] = 0;
        }
        const int kb = kt * 4 + q;
#pragma unroll
        for (int n = 0; n < 8; ++n) {
            const bf16x8 wfrag =
                *(const bf16x8*)(Wp + (size_t)kb * 1024 + (n * 16 + c16) * 8);
            acc[n] = __builtin_amdgcn_mfma_f32_16x16x32_bf16(wfrag, afrag, acc[n], 0, 0, 0);
        }
    }
#pragma unroll
    for (int n = 0; n < 8; ++n) {
        const int col = n * 16 + q * 4;
        const float4 b4 = *(const float4*)(bias + col);
        bf16x4 o;
        o[0] = f2bf(acc[n][0] + b4.x); o[1] = f2bf(acc[n][1] + b4.y);
        o[2] = f2bf(acc[n][2] + b4.z); o[3] = f2bf(acc[n][3] + b4.w);
        *(bf16x4*)(Cb + (size_t)row * HH + col) = o;
    }
}

// Fused 4 node linears: one A-fragment load feeds 4 weight matrices.
template<bool ABN>
__global__ __launch_bounds__(256, 2)
void fused4_k(const short* __restrict__ hb, const float* __restrict__ hf,
              const float* __restrict__ bnp,
              const short* __restrict__ w0, const short* __restrict__ w1,
              const short* __restrict__ w2, const short* __restrict__ w3,
              const float* __restrict__ b0, const float* __restrict__ b1,
              const float* __restrict__ b2, const float* __restrict__ b3,
              float* __restrict__ Ah, short* __restrict__ Bh,
              short* __restrict__ Dh, short* __restrict__ Eh)
{
    const int lane = threadIdx.x & 63;
    const int wave = threadIdx.x >> 6;
    const int q = lane >> 4;
    const int c16 = lane & 15;
    const int row = blockIdx.x * 64 + wave * 16 + c16;

    f32x4 acc[4][8];
#pragma unroll
    for (int t = 0; t < 4; ++t)
#pragma unroll
        for (int n = 0; n < 8; ++n) acc[t][n] = (f32x4){0.f, 0.f, 0.f, 0.f};

    const short* const ws[4] = {w0, w1, w2, w3};
#pragma unroll
    for (int kt = 0; kt < 4; ++kt) {
        const int kbase = kt * 32 + q * 8;
        bf16x8 afrag;
        if (!ABN) {
            afrag = *(const bf16x8*)(hb + (size_t)row * HH + kbase);
        } else {
            const float* p = hf + (size_t)row * HH + kbase;
            const float4 x = *(const float4*)p;
            const float4 y = *(const float4*)(p + 4);
            const float4 s0 = *(const float4*)(bnp + kbase);
            const float4 s1 = *(const float4*)(bnp + kbase + 4);
            const float4 t0 = *(const float4*)(bnp + HH + kbase);
            const float4 t1 = *(const float4*)(bnp + HH + kbase + 4);
            const float xv[8] = {x.x, x.y, x.z, x.w, y.x, y.y, y.z, y.w};
            const float scv[8] = {s0.x, s0.y, s0.z, s0.w, s1.x, s1.y, s1.z, s1.w};
            const float shv[8] = {t0.x, t0.y, t0.z, t0.w, t1.x, t1.y, t1.z, t1.w};
#pragma unroll
            for (int j = 0; j < 8; ++j)
                afrag[j] = f2bf(fmaxf(fmaf(xv[j], scv[j], shv[j]), 0.f));
        }
        const int kb = kt * 4 + q;
#pragma unroll
        for (int t = 0; t < 4; ++t)
#pragma unroll
            for (int n = 0; n < 8; ++n) {
                const bf16x8 wfrag =
                    *(const bf16x8*)(ws[t] + (size_t)kb * 1024 + (n * 16 + c16) * 8);
                acc[t][n] = __builtin_amdgcn_mfma_f32_16x16x32_bf16(wfrag, afrag, acc[t][n], 0, 0, 0);
            }
    }

    const float* const bs[4] = {b0, b1, b2, b3};
#pragma unroll
    for (int t = 0; t < 4; ++t) {
#pragma unroll
        for (int n = 0; n < 8; ++n) {
            const int col = n * 16 + q * 4;
            const float4 b4 = *(const float4*)(bs[t] + col);
            const float v[4] = {acc[t][n][0] + b4.x, acc[t][n][1] + b4.y,
                                acc[t][n][2] + b4.z, acc[t][n][3] + b4.w};
            if (t == 0) {
                *(float4*)(Ah + (size_t)row * HH + col) = make_float4(v[0], v[1], v[2], v[3]);
            } else {
                bf16x4 o;
#pragma unroll
                for (int j = 0; j < 4; ++j) o[j] = f2bf(v[j]);
                short* dstp = (t == 1) ? Bh : ((t == 2) ? Dh : Eh);
                *(bf16x4*)(dstp + (size_t)row * HH + col) = o;
            }
        }
    }
}

// Layer-1 fused edge+seg: e_new1 in regs (NO store), e-BN stats, sigmoid
// seg-sum -> hnew. Wave = 8 nodes; slot = lane>>4, cg = lane&15.
__global__ __launch_bounds__(256)
void edge1seg_k(const float* __restrict__ ef, const int* __restrict__ eidx,
                const int* __restrict__ src_s, const int* __restrict__ rowptr,
                const float* __restrict__ G,
                const short* __restrict__ Dh, const short* __restrict__ Eh,
                const short* __restrict__ Bh, const float* __restrict__ Ah,
                float* __restrict__ hnew, float* __restrict__ pbuf)
{
    const int wv = threadIdx.x >> 6;
    const int lane = threadIdx.x & 63;
    const int slot = lane >> 4;
    const int cg = lane & 15;
    const int col = cg * 8;
    const int n0 = (blockIdx.x * 4 + wv) * 8;

    const float4 g00 = *(const float4*)(G + col);
    const float4 g01 = *(const float4*)(G + col + 4);
    const float4 g10 = *(const float4*)(G + HH + col);
    const float4 g11 = *(const float4*)(G + HH + col + 4);
    const float4 gb0 = *(const float4*)(G + 2 * HH + col);
    const float4 gb1 = *(const float4*)(G + 2 * HH + col + 4);
    const float G0v[8] = {g00.x, g00.y, g00.z, g00.w, g01.x, g01.y, g01.z, g01.w};
    const float G1v[8] = {g10.x, g10.y, g10.z, g10.w, g11.x, g11.y, g11.z, g11.w};
    const float GBv[8] = {gb0.x, gb0.y, gb0.z, gb0.w, gb1.x, gb1.y, gb1.z, gb1.w};

    float esa[8] = {}, esq[8] = {};

    for (int nn = 0; nn < 8; ++nn) {
        const int n = n0 + nn;
        const int k0 = rowptr[n], k1 = rowptr[n + 1];
        const bf16x8 ehn = *(const bf16x8*)(Eh + (size_t)n * HH + col);
        float ehv[8];
#pragma unroll
        for (int j = 0; j < 8; ++j) ehv[j] = bf2f(ehn[j]);
        float num[8] = {}, den[8] = {};
        for (int k = k0 + slot; k < k1; k += 4) {
            const int e = eidx[k];
            const int s = src_s[k];
            const float f0 = ef[(size_t)e * 2];
            const float f1 = ef[(size_t)e * 2 + 1];
            const bf16x8 dh = *(const bf16x8*)(Dh + (size_t)s * HH + col);
            const bf16x8 bh = *(const bf16x8*)(Bh + (size_t)s * HH + col);
#pragma unroll
            for (int j = 0; j < 8; ++j) {
                const float v = fmaf(f0, G0v[j], fmaf(f1, G1v[j], GBv[j]))
                                + bf2f(dh[j]) + ehv[j];
                esa[j] += v; esq[j] += v * v;
                const float sg = 1.f / (1.f + __expf(-v));
                den[j] += sg;
                num[j] = fmaf(sg, bf2f(bh[j]), num[j]);
            }
        }
#pragma unroll
        for (int j = 0; j < 8; ++j) {
            num[j] += __shfl_xor(num[j], 16, 64);
            den[j] += __shfl_xor(den[j], 16, 64);
            num[j] += __shfl_xor(num[j], 32, 64);
            den[j] += __shfl_xor(den[j], 32, 64);
        }
        if (slot == 0) {
            const size_t idx = (size_t)n * HH + col;
            const float4 a0 = *(const float4*)(Ah + idx);
            const float4 a1 = *(const float4*)(Ah + idx + 4);
            const float av[8] = {a0.x, a0.y, a0.z, a0.w, a1.x, a1.y, a1.z, a1.w};
            float x[8];
#pragma unroll
            for (int j = 0; j < 8; ++j) x[j] = av[j] + num[j] / (den[j] + 1e-6f);
            *(float4*)(hnew + idx) = make_float4(x[0], x[1], x[2], x[3]);
            *(float4*)(hnew + idx + 4) = make_float4(x[4], x[5], x[6], x[7]);
        }
    }

    __shared__ float sred[16][136];
    const int er = threadIdx.x >> 4;
    const int slotp = (blockIdx.x & 63) * 256;
#pragma unroll
    for (int j = 0; j < 8; ++j) sred[er][col + j] = esa[j];
    __syncthreads();
    for (int s2 = 8; s2 > 0; s2 >>= 1) {
        if (er < s2)
#pragma unroll
            for (int j = 0; j < 8; ++j) sred[er][col + j] += sred[er + s2][col + j];
        __syncthreads();
    }
    if (er == 0)
#pragma unroll
        for (int j = 0; j < 8; ++j) atomicAdd(pbuf + slotp + col + j, sred[0][col + j]);
    __syncthreads();
#pragma unroll
    for (int j = 0; j < 8; ++j) sred[er][col + j] = esq[j];
    __syncthreads();
    for (int s2 = 8; s2 > 0; s2 >>= 1) {
        if (er < s2)
#pragma unroll
            for (int j = 0; j < 8; ++j) sred[er][col + j] += sred[er + s2][col + j];
        __syncthreads();
    }
    if (er == 0)
#pragma unroll
        for (int j = 0; j < 8; ++j) atomicAdd(pbuf + slotp + 128 + col + j, sred[0][col + j]);
}

// Fold e-BN into the rank-2 edge map: Gm = [G0*sc | G1*sc | GB*sc+sh | sc].
__global__ void gm_k(const float* __restrict__ G, const float* __restrict__ bnpe,
                     float* __restrict__ Gm)
{
    const int c = threadIdx.x;
    const float sc = bnpe[c], sh = bnpe[128 + c];
    Gm[c] = G[c] * sc;
    Gm[128 + c] = G[HH + c] * sc;
    Gm[256 + c] = fmaf(G[2 * HH + c], sc, sh);
    Gm[384 + c] = sc;
}

// Layer-2 edge GEMM: A = relu(bn(e_new1)) RECOMPUTED on the fly from
// rank-2 map + Dh0/Eh0 gathers (no 160MB enew read). 2 rows/lane; acc init
// = bias + Dh1[src] + Eh1[dst]. Writes e_new2 -> enew (read by seg_reduce_v).
__global__ __launch_bounds__(256)
void edge2_k(const int* __restrict__ eidx, const float* __restrict__ ef,
             const float* __restrict__ Gm,
             const short* __restrict__ Dh0, const short* __restrict__ Eh0,
             const short* __restrict__ Dh1, const short* __restrict__ Eh1,
             const int* __restrict__ src_s, const int* __restrict__ dst_s,
             const short* __restrict__ Wp, const float* __restrict__ bias,
             short* __restrict__ enew)
{
    const int lane = threadIdx.x & 63;
    const int wave = threadIdx.x >> 6;
    const int q = lane >> 4;
    const int c16 = lane & 15;
    const int row0 = blockIdx.x * 128 + wave * 16 + c16;
    const int row1 = row0 + 64;

    const int s0 = src_s[row0], d0 = dst_s[row0];
    const int s1 = src_s[row1], d1 = dst_s[row1];
    const int e0 = eidx[row0], e1 = eidx[row1];
    const float2 ef0 = *(const float2*)(ef + (size_t)e0 * 2);
    const float2 ef1 = *(const float2*)(ef + (size_t)e1 * 2);

    f32x4 acc[2][8];
#pragma unroll
    for (int n = 0; n < 8; ++n) {
        const int col = n * 16 + q * 4;
        const float4 b4 = *(const float4*)(bias + col);
        const bf16x4 dh0 = *(const bf16x4*)(Dh1 + (size_t)s0 * HH + col);
        const bf16x4 eh0 = *(const bf16x4*)(Eh1 + (size_t)d0 * HH + col);
        const bf16x4 dh1 = *(const bf16x4*)(Dh1 + (size_t)s1 * HH + col);
        const bf16x4 eh1 = *(const bf16x4*)(Eh1 + (size_t)d1 * HH + col);
        const float bb[4] = {b4.x, b4.y, b4.z, b4.w};
#pragma unroll
        for (int j = 0; j < 4; ++j) {
            acc[0][n][j] = bb[j] + bf2f(dh0[j]) + bf2f(eh0[j]);
            acc[1][n][j] = bb[j] + bf2f(dh1[j]) + bf2f(eh1[j]);
        }
    }

#pragma unroll
    for (int kt = 0; kt < 4; ++kt) {
        const int kbase = kt * 32 + q * 8;
        const float4 p0 = *(const float4*)(Gm + kbase);
        const float4 p1 = *(const float4*)(Gm + kbase + 4);
        const float4 p2 = *(const float4*)(Gm + 128 + kbase);
        const float4 p3 = *(const float4*)(Gm + 128 + kbase + 4);
        const float4 p4 = *(const float4*)(Gm + 256 + kbase);
        const float4 p5 = *(const float4*)(Gm + 256 + kbase + 4);
        const float4 p6 = *(const float4*)(Gm + 384 + kbase);
        const float4 p7 = *(const float4*)(Gm + 384 + kbase + 4);
        const float g0s[8] = {p0.x, p0.y, p0.z, p0.w, p1.x, p1.y, p1.z, p1.w};
        const float g1s[8] = {p2.x, p2.y, p2.z, p2.w, p3.x, p3.y, p3.z, p3.w};
        const float gbs[8] = {p4.x, p4.y, p4.z, p4.w, p5.x, p5.y, p5.z, p5.w};
        const float scv[8] = {p6.x, p6.y, p6.z, p6.w, p7.x, p7.y, p7.z, p7.w};
        const bf16x8 dA0 = *(const bf16x8*)(Dh0 + (size_t)s0 * HH + kbase);
        const bf16x8 eA0 = *(const bf16x8*)(Eh0 + (size_t)d0 * HH + kbase);
        const bf16x8 dA1 = *(const bf16x8*)(Dh0 + (size_t)s1 * HH + kbase);
        const bf16x8 eA1 = *(const bf16x8*)(Eh0 + (size_t)d1 * HH + kbase);
        bf16x8 a0, a1;
#pragma unroll
        for (int j = 0; j < 8; ++j) {
            float t0 = fmaf(scv[j], bf2f(dA0[j]) + bf2f(eA0[j]), gbs[j]);
            t0 = fmaf(ef0.x, g0s[j], fmaf(ef0.y, g1s[j], t0));
            a0[j] = f2bf(fmaxf(t0, 0.f));
            float t1 = fmaf(scv[j], bf2f(dA1[j]) + bf2f(eA1[j]), gbs[j]);
            t1 = fmaf(ef1.x, g0s[j], fmaf(ef1.y, g1s[j], t1));
            a1[j] = f2bf(fmaxf(t1, 0.f));
        }
        const int kb = kt * 4 + q;
#pragma unroll
        for (int n = 0; n < 8; ++n) {
            const bf16x8 wfrag =
                *(const bf16x8*)(Wp + (size_t)kb * 1024 + (n * 16 + c16) * 8);
            acc[0][n] = __builtin_amdgcn_mfma_f32_16x16x32_bf16(wfrag, a0, acc[0][n], 0, 0, 0);
            acc[1][n] = __builtin_amdgcn_mfma_f32_16x16x32_bf16(wfrag, a1, acc[1][n], 0, 0, 0);
        }
    }

#pragma unroll
    for (int n = 0; n < 8; ++n) {
        const int col = n * 16 + q * 4;
        bf16x4 o0, o1;
#pragma unroll
        for (int j = 0; j < 4; ++j) {
            o0[j] = f2bf(acc[0][n][j]);
            o1[j] = f2bf(acc[1][n][j]);
        }
        *(bf16x4*)(enew + (size_t)row0 * HH + col) = o0;
        *(bf16x4*)(enew + (size_t)row1 * HH + col) = o1;
    }
}

// Vectorized per-node CSR reduction (reads e_new2) + fused h-BN stats.
__global__ __launch_bounds__(256)
void seg_reduce_v(const short* __restrict__ enew, const int* __restrict__ rowptr,
                  const int* __restrict__ src_s, const short* __restrict__ Bh,
                  const float* __restrict__ Ah, float* __restrict__ hnew,
                  float* __restrict__ pbuf)
{
    const int wv = threadIdx.x >> 6;
    const int lane = threadIdx.x & 63;
    const int slot = lane >> 4;
    const int cg = lane & 15;
    const int col = cg * 8;
    const int n0 = (blockIdx.x * 4 + wv) * 8;
    float sa[8] = {}, qa[8] = {};
    for (int nn = 0; nn < 8; ++nn) {
        const int n = n0 + nn;
        const int k0 = rowptr[n], k1 = rowptr[n + 1];
        float num[8] = {}, den[8] = {};
        for (int k = k0 + slot; k < k1; k += 4) {
            const bf16x8 ev = *(const bf16x8*)(enew + (size_t)k * HH + col);
            const int s = src_s[k];
            const bf16x8 bv = *(const bf16x8*)(Bh + (size_t)s * HH + col);
#pragma unroll
            for (int j = 0; j < 8; ++j) {
                const float sg = 1.f / (1.f + __expf(-bf2f(ev[j])));
                den[j] += sg;
                num[j] = fmaf(sg, bf2f(bv[j]), num[j]);
            }
        }
#pragma unroll
        for (int j = 0; j < 8; ++j) {
            num[j] += __shfl_xor(num[j], 16, 64);
            den[j] += __shfl_xor(den[j], 16, 64);
            num[j] += __shfl_xor(num[j], 32, 64);
            den[j] += __shfl_xor(den[j], 32, 64);
        }
        if (slot == 0) {
            const size_t idx = (size_t)n * HH + col;
            const float4 a0 = *(const float4*)(Ah + idx);
            const float4 a1 = *(const float4*)(Ah + idx + 4);
            const float av[8] = {a0.x, a0.y, a0.z, a0.w, a1.x, a1.y, a1.z, a1.w};
            float x[8];
#pragma unroll
            for (int j = 0; j < 8; ++j) {
                x[j] = av[j] + num[j] / (den[j] + 1e-6f);
                sa[j] += x[j]; qa[j] += x[j] * x[j];
            }
            *(float4*)(hnew + idx) = make_float4(x[0], x[1], x[2], x[3]);
            *(float4*)(hnew + idx + 4) = make_float4(x[4], x[5], x[6], x[7]);
        }
    }
    if (slot == 0) {
        const int sl = (blockIdx.x & 63) * 256;
#pragma unroll
        for (int j = 0; j < 8; ++j) {
            atomicAdd(pbuf + sl + col + j, sa[j]);
            atomicAdd(pbuf + sl + 128 + col + j, qa[j]);
        }
    }
}

// Fused readout: logits = relu(relu(bn(hnew)) @ w1 + b1) @ w2 + b2.
__global__ __launch_bounds__(256)
void readout_k(const float* __restrict__ hnew, const float* __restrict__ bnp,
               const short* __restrict__ Wp, const float* __restrict__ b1,
               const float* __restrict__ w2, const float* __restrict__ b2,
               float* __restrict__ out)
{
    const int lane = threadIdx.x & 63;
    const int wave = threadIdx.x >> 6;
    const int q = lane >> 4;
    const int c16 = lane & 15;
    const int row = blockIdx.x * 64 + wave * 16 + c16;

    f32x4 acc[8];
#pragma unroll
    for (int n = 0; n < 8; ++n) acc[n] = (f32x4){0.f, 0.f, 0.f, 0.f};

#pragma unroll
    for (int kt = 0; kt < 4; ++kt) {
        const int kbase = kt * 32 + q * 8;
        const float* p = hnew + (size_t)row * HH + kbase;
        const float4 x = *(const float4*)p;
        const float4 y = *(const float4*)(p + 4);
        const float4 s0 = *(const float4*)(bnp + kbase);
        const float4 s1 = *(const float4*)(bnp + kbase + 4);
        const float4 t0 = *(const float4*)(bnp + HH + kbase);
        const float4 t1 = *(const float4*)(bnp + HH + kbase + 4);
        const float xv[8] = {x.x, x.y, x.z, x.w, y.x, y.y, y.z, y.w};
        const float scv[8] = {s0.x, s0.y, s0.z, s0.w, s1.x, s1.y, s1.z, s1.w};
        const float shv[8] = {t0.x, t0.y, t0.z, t0.w, t1.x, t1.y, t1.z, t1.w};
        bf16x8 afrag;
#pragma unroll
        for (int j = 0; j < 8; ++j)
            afrag[j] = f2bf(fmaxf(fmaf(xv[j], scv[j], shv[j]), 0.f));
        const int kb = kt * 4 + q;
#pragma unroll
        for (int n = 0; n < 8; ++n) {
            const bf16x8 wfrag =
                *(const bf16x8*)(Wp + (size_t)kb * 1024 + (n * 16 + c16) * 8);
            acc[n] = __builtin_amdgcn_mfma_f32_16x16x32_bf16(wfrag, afrag, acc[n], 0, 0, 0);
        }
    }

    float part[NCLS] = {};
#pragma unroll
    for (int n = 0; n < 8; ++n) {
        const int col = n * 16 + q * 4;
        const float4 b4 = *(const float4*)(b1 + col);
        const float bb[4] = {b4.x, b4.y, b4.z, b4.w};
#pragma unroll
        for (int j = 0; j < 4; ++j) {
            const float zv = fmaxf(acc[n][j] + bb[j], 0.f);
#pragma unroll
            for (int t = 0; t < NCLS; ++t)
                part[t] = fmaf(zv, w2[(col + j) * NCLS + t], part[t]);
        }
    }
#pragma unroll
    for (int t = 0; t < NCLS; ++t) {
        part[t] += __shfl_xor(part[t], 16, 64);
        part[t] += __shfl_xor(part[t], 32, 64);
    }
    if (q == 0) {
#pragma unroll
        for (int t = 0; t < NCLS; ++t)
            out[(size_t)row * NCLS + t] = part[t] + b2[t];
    }
}

// Pack all weight matrices to bf16 fragments: Wp[kb][col][8] = W[kb*8+j][col].
__global__ __launch_bounds__(256)
void prepack_k(const float* __restrict__ enc_nw, const float* __restrict__ lin_w,
               const float* __restrict__ mlp_w1, short* __restrict__ wp)
{
    const int t = blockIdx.x * 256 + threadIdx.x;
    if (t >= 260 * 128) return;
    const int kbg = t >> 7, col = t & 127;
    const int kb0[11]  = {0, 100, 116, 132, 148, 164, 180, 196, 212, 228, 244};
    const int psel[11] = {0, 1, 1, 1, 1, 1, 1, 1, 1, 1, 2};
    const int soff[11] = {0, 0 * 16384, 1 * 16384, 3 * 16384, 4 * 16384,
                          5 * 16384, 6 * 16384, 7 * 16384, 8 * 16384, 9 * 16384, 0};
    const int Ksrc[11] = {KIN, 128, 128, 128, 128, 128, 128, 128, 128, 128, 128};
    int e = 10;
    while (e > 0 && kbg < kb0[e]) --e;
    const float* base = (psel[e] == 0) ? enc_nw : ((psel[e] == 1) ? lin_w : mlp_w1);
    const int kbl = kbg - kb0[e];
    bf16x8 o;
#pragma unroll
    for (int j = 0; j < 8; ++j) {
        const int k = kbl * 8 + j;
        const float v = (k < Ksrc[e]) ? base[(size_t)soff[e] + (size_t)k * HH + col] : 0.f;
        o[j] = f2bf(v);
    }
    *(bf16x8*)(wp + (size_t)kbg * 1024 + col * 8) = o;
}

// Rank-2 collapse of layer-1 edge GEMM.
__global__ void gpre_k(const float* __restrict__ enc_ew, const float* __restrict__ enc_eb,
                       const float* __restrict__ Wc, const float* __restrict__ bc,
                       float* __restrict__ G)
{
    const int c = threadIdx.x;
    float a0 = 0.f, a1 = 0.f, ab = 0.f;
    for (int k = 0; k < HH; ++k) {
        const float w = Wc[k * HH + c];
        a0 = fmaf(enc_ew[k], w, a0);
        a1 = fmaf(enc_ew[HH + k], w, a1);
        ab = fmaf(enc_eb[k], w, ab);
    }
    G[c] = a0; G[HH + c] = a1; G[2 * HH + c] = ab + bc[c];
}

// ---- CSR build ----
__global__ __launch_bounds__(256)
void hist_k(const int* __restrict__ dst, int* __restrict__ cnt)
{
    const int e = blockIdx.x * 256 + threadIdx.x;
    if (e < NE) atomicAdd(cnt + dst[e], 1);
}

__global__ __launch_bounds__(1024)
void scan_k(const int* __restrict__ cnt, int* __restrict__ rowptr, int* __restrict__ wr)
{
    __shared__ int s[1024];
    const int t = threadIdx.x;
    const int base = t * 40;
    int sum = 0;
    for (int i = 0; i < 40; ++i) {
        const int idx = base + i;
        if (idx < NN) sum += cnt[idx];
    }
    s[t] = sum;
    __syncthreads();
    for (int off = 1; off < 1024; off <<= 1) {
        const int v = (t >= off) ? s[t - off] : 0;
        __syncthreads();
        s[t] += v;
        __syncthreads();
    }
    int run = (t == 0) ? 0 : s[t - 1];
    for (int i = 0; i < 40; ++i) {
        const int idx = base + i;
        if (idx < NN) {
            rowptr[idx] = run;
            wr[idx] = run;
            run += cnt[idx];
        }
    }
    if (t == 1023) rowptr[NN] = s[1023];
}

__global__ __launch_bounds__(256)
void scatter_k(const int* __restrict__ dst, const int* __restrict__ src,
               int* __restrict__ wr, int* __restrict__ eidx,
               int* __restrict__ src_s, int* __restrict__ dst_s)
{
    const int e = blockIdx.x * 256 + threadIdx.x;
    if (e < NE) {
        const int d = dst[e];
        const int p = atomicAdd(wr + d, 1);
        eidx[p] = e;
        src_s[p] = src[e];
        dst_s[p] = d;
    }
}

// h-BN column stats -> pbuf partials.
__global__ __launch_bounds__(256)
void hstats_k(const float* __restrict__ hnew, float* __restrict__ pbuf)
{
    const int tid = threadIdx.x;
    const int c = tid & 127, sub = tid >> 7;
    const int r0 = blockIdx.x * 256;
    float sa = 0.f, qa = 0.f;
    for (int i = sub; i < 256; i += 2) {
        const int r = r0 + i;
        if (r >= NN) break;
        const float x = hnew[(size_t)r * HH + c];
        sa += x; qa += x * x;
    }
    __shared__ float red[256];
    red[tid] = sa; __syncthreads();
    if (tid < 128) atomicAdd(pbuf + (blockIdx.x & 63) * 256 + c, red[tid] + red[tid + 128]);
    __syncthreads();
    red[tid] = qa; __syncthreads();
    if (tid < 128) atomicAdd(pbuf + (blockIdx.x & 63) * 256 + 128 + c, red[tid] + red[tid + 128]);
}

// BN params from 64-slot partials.
__global__ void make_bnp2(const float* __restrict__ pbuf, const float* __restrict__ g,
                          const float* __restrict__ b, float cntInv,
                          float* __restrict__ out)
{
    const int c = threadIdx.x;
    float s = 0.f, q = 0.f;
    for (int i = 0; i < 64; ++i) {
        s += pbuf[i * 256 + c];
        q += pbuf[i * 256 + 128 + c];
    }
    const float m = s * cntInv;
    const float var = q * cntInv - m * m;
    const float rs = rsqrtf(var + 1e-5f);
    const float sc = g[c] * rs;
    out[c] = sc;
    out[128 + c] = b[c] - m * sc;
}

extern "C" void kernel_launch(void* const* d_in, const int* in_sizes, int n_in,
                              void* d_out, int out_size, void* d_ws, size_t ws_size,
                              hipStream_t stream)
{
    const float* node_feat = (const float*)d_in[0];
    const float* edge_feat = (const float*)d_in[1];
    const int*   src       = (const int*)d_in[2];
    const int*   dst       = (const int*)d_in[3];
    const float* enc_nw    = (const float*)d_in[4];
    const float* enc_nb    = (const float*)d_in[5];
    const float* enc_ew    = (const float*)d_in[6];
    const float* enc_eb    = (const float*)d_in[7];
    const float* lin_w     = (const float*)d_in[8];
    const float* lin_b     = (const float*)d_in[9];
    const float* bnh_g     = (const float*)d_in[10];
    const float* bnh_b     = (const float*)d_in[11];
    const float* bne_g     = (const float*)d_in[12];
    const float* bne_b     = (const float*)d_in[13];
    const float* mlp_w1    = (const float*)d_in[14];
    const float* mlp_b1    = (const float*)d_in[15];
    const float* mlp_w2    = (const float*)d_in[16];
    const float* mlp_b2    = (const float*)d_in[17];
    float* out = (float*)d_out;

    char* base = (char*)d_ws;
    size_t off = 0;
    auto alloc = [&](size_t bytes) -> void* {
        void* p = base + off;
        off = (off + bytes + 255) & ~(size_t)255;
        return p;
    };
    const size_t NH = (size_t)NN * HH;
    float* hnew  = (float*)alloc(NH * 4);
    float* Ah    = (float*)alloc(NH * 4);
    short* h0    = (short*)alloc(NH * 2);     // encoder out; reused as Bh1
    short* Bh0   = (short*)alloc(NH * 2);
    short* Dh0   = (short*)alloc(NH * 2);
    short* Eh0   = (short*)alloc(NH * 2);
    short* Dh1   = (short*)alloc(NH * 2);
    short* Eh1   = (short*)alloc(NH * 2);
    short* enew  = (short*)alloc((size_t)NE * HH * 2);   // e_new2 only
    short* wpack = (short*)alloc((size_t)260 * 1024 * 2);
    float* G     = (float*)alloc(384 * 4);
    float* Gm    = (float*)alloc(512 * 4);
    float* bnpe  = (float*)alloc(256 * 4);
    float* bnph  = (float*)alloc(256 * 4);
    float* pbe   = (float*)alloc(16384 * 4);
    float* pbh0  = (float*)alloc(16384 * 4);
    float* pbh1  = (float*)alloc(16384 * 4);
    int* cnt     = (int*)alloc(NN * 4);
    int* rowptr  = (int*)alloc((NN + 1) * 4);
    int* wr      = (int*)alloc(NN * 4);
    int* eidx    = (int*)alloc((size_t)NE * 4);
    int* src_s   = (int*)alloc((size_t)NE * 4);
    int* dst_s   = (int*)alloc((size_t)NE * 4);

    const dim3 blk(256);

    hipMemsetAsync(cnt, 0, NN * 4, stream);
    hipMemsetAsync(pbe, 0, 3 * 16384 * 4, stream);   // pbe,pbh0,pbh1 contiguous
    hist_k<<<2500, blk, 0, stream>>>(dst, cnt);
    scan_k<<<1, 1024, 0, stream>>>(cnt, rowptr, wr);
    scatter_k<<<2500, blk, 0, stream>>>(dst, src, wr, eidx, src_s, dst_s);
    prepack_k<<<130, blk, 0, stream>>>(enc_nw, lin_w, mlp_w1, wpack);
    gpre_k<<<1, 128, 0, stream>>>(enc_ew, enc_eb, lin_w + 2 * 16384, lin_b + 2 * HH, G);

    // encoder: h0 = bf16(node_feat @ enc_nw + enc_nb)
    mfma_gemm<25, true><<<625, blk, 0, stream>>>(node_feat, wpack, enc_nb, h0, KIN);

    // ---- layer 0 ----
    {
        const float* Bv = lin_b;
        fused4_k<false><<<625, blk, 0, stream>>>(
            h0, nullptr, nullptr,
            wpack + (size_t)100 * 1024, wpack + (size_t)116 * 1024,
            wpack + (size_t)132 * 1024, wpack + (size_t)148 * 1024,
            Bv + 0 * HH, Bv + 1 * HH, Bv + 3 * HH, Bv + 4 * HH,
            Ah, Bh0, Dh0, Eh0);
        edge1seg_k<<<1250, blk, 0, stream>>>(edge_feat, eidx, src_s, rowptr, G,
                                             Dh0, Eh0, Bh0, Ah, hnew, pbe);
        make_bnp2<<<1, 128, 0, stream>>>(pbe, bne_g, bne_b, 1.f / NE, bnpe);
        gm_k<<<1, 128, 0, stream>>>(G, bnpe, Gm);
        hstats_k<<<157, blk, 0, stream>>>(hnew, pbh0);
        make_bnp2<<<1, 128, 0, stream>>>(pbh0, bnh_g, bnh_b, 1.f / NN, bnph);
    }

    // ---- layer 1 ----
    {
        const float* Bv = lin_b + 5 * HH;
        short* Bh1 = h0;   // h0 dead after layer-0 fused4
        fused4_k<true><<<625, blk, 0, stream>>>(
            nullptr, hnew, bnph,
            wpack + (size_t)164 * 1024, wpack + (size_t)180 * 1024,
            wpack + (size_t)212 * 1024, wpack + (size_t)228 * 1024,
            Bv + 0 * HH, Bv + 1 * HH, Bv + 3 * HH, Bv + 4 * HH,
            Ah, Bh1, Dh1, Eh1);
        edge2_k<<<5000, blk, 0, stream>>>(eidx, edge_feat, Gm, Dh0, Eh0, Dh1, Eh1,
                                          src_s, dst_s, wpack + (size_t)196 * 1024,
                                          Bv + 2 * HH, enew);
        seg_reduce_v<<<1250, blk, 0, stream>>>(enew, rowptr, src_s, Bh1, Ah, hnew, pbh1);
        make_bnp2<<<1, 128, 0, stream>>>(pbh1, bnh_g + HH, bnh_b + HH, 1.f / NN, bnph);
    }

    // fused readout
    readout_k<<<625, blk, 0, stream>>>(hnew, bnph, wpack + (size_t)244 * 1024,
                                       mlp_b1, mlp_w2, mlp_b2, out);
}

// Round 9
// 778.938 us; speedup vs baseline: 1.5399x; 1.0973x over previous
//
#include <hip/hip_runtime.h>
#include <math.h>

#define NN 40000
#define NE 640000
#define KIN 776
#define HH 128
#define NCLS 5

typedef __attribute__((ext_vector_type(8))) short bf16x8;
typedef __attribute__((ext_vector_type(4))) short bf16x4;
typedef __attribute__((ext_vector_type(4))) float f32x4;

__device__ __forceinline__ float bf2f(short u) {
    return __uint_as_float(((unsigned)(unsigned short)u) << 16);
}
__device__ __forceinline__ short f2bf(float f) {          // RNE
    unsigned u = __float_as_uint(f);
    u += 0x7fffu + ((u >> 16) & 1u);
    return (short)(u >> 16);
}

// MFMA GEMM (encoder): C[M,128] = f32A[M,K] @ W[K,128] + bias -> bf16.
template<int NSTEP, bool TAIL8>
__global__ __launch_bounds__(256)
void mfma_gemm(const float* __restrict__ Af, const short* __restrict__ Wp,
               const float* __restrict__ bias, short* __restrict__ Cb, int K)
{
    const int lane = threadIdx.x & 63;
    const int wave = threadIdx.x >> 6;
    const int q = lane >> 4;
    const int c16 = lane & 15;
    const int row = blockIdx.x * 64 + wave * 16 + c16;

    f32x4 acc[8];
#pragma unroll
    for (int n = 0; n < 8; ++n) acc[n] = (f32x4){0.f, 0.f, 0.f, 0.f};

    for (int kt = 0; kt < NSTEP; ++kt) {
        bf16x8 afrag;
        const int kbase = kt * 32 + q * 8;
        if (!TAIL8 || kt < NSTEP - 1 || q == 0) {
            const float* p = Af + (size_t)row * K + kbase;
            const float4 x = *(const float4*)p;
            const float4 y = *(const float4*)(p + 4);
            afrag[0] = f2bf(x.x); afrag[1] = f2bf(x.y);
            afrag[2] = f2bf(x.z); afrag[3] = f2bf(x.w);
            afrag[4] = f2bf(y.x); afrag[5] = f2bf(y.y);
            afrag[6] = f2bf(y.z); afrag[7] = f2bf(y.w);
        } else {
#pragma unroll
            for (int j = 0; j < 8; ++j) afrag[j] = 0;
        }
        const int kb = kt * 4 + q;
#pragma unroll
        for (int n = 0; n < 8; ++n) {
            const bf16x8 wfrag =
                *(const bf16x8*)(Wp + (size_t)kb * 1024 + (n * 16 + c16) * 8);
            acc[n] = __builtin_amdgcn_mfma_f32_16x16x32_bf16(wfrag, afrag, acc[n], 0, 0, 0);
        }
    }
#pragma unroll
    for (int n = 0; n < 8; ++n) {
        const int col = n * 16 + q * 4;
        const float4 b4 = *(const float4*)(bias + col);
        bf16x4 o;
        o[0] = f2bf(acc[n][0] + b4.x); o[1] = f2bf(acc[n][1] + b4.y);
        o[2] = f2bf(acc[n][2] + b4.z); o[3] = f2bf(acc[n][3] + b4.w);
        *(bf16x4*)(Cb + (size_t)row * HH + col) = o;
    }
}

// Fused 4 node linears: one A-fragment load feeds 4 weight matrices.
template<bool ABN>
__global__ __launch_bounds__(256, 2)
void fused4_k(const short* __restrict__ hb, const float* __restrict__ hf,
              const float* __restrict__ bnp,
              const short* __restrict__ w0, const short* __restrict__ w1,
              const short* __restrict__ w2, const short* __restrict__ w3,
              const float* __restrict__ b0, const float* __restrict__ b1,
              const float* __restrict__ b2, const float* __restrict__ b3,
              float* __restrict__ Ah, short* __restrict__ Bh,
              short* __restrict__ Dh, short* __restrict__ Eh)
{
    const int lane = threadIdx.x & 63;
    const int wave = threadIdx.x >> 6;
    const int q = lane >> 4;
    const int c16 = lane & 15;
    const int row = blockIdx.x * 64 + wave * 16 + c16;

    f32x4 acc[4][8];
#pragma unroll
    for (int t = 0; t < 4; ++t)
#pragma unroll
        for (int n = 0; n < 8; ++n) acc[t][n] = (f32x4){0.f, 0.f, 0.f, 0.f};

    const short* const ws[4] = {w0, w1, w2, w3};
#pragma unroll
    for (int kt = 0; kt < 4; ++kt) {
        const int kbase = kt * 32 + q * 8;
        bf16x8 afrag;
        if (!ABN) {
            afrag = *(const bf16x8*)(hb + (size_t)row * HH + kbase);
        } else {
            const float* p = hf + (size_t)row * HH + kbase;
            const float4 x = *(const float4*)p;
            const float4 y = *(const float4*)(p + 4);
            const float4 s0 = *(const float4*)(bnp + kbase);
            const float4 s1 = *(const float4*)(bnp + kbase + 4);
            const float4 t0 = *(const float4*)(bnp + HH + kbase);
            const float4 t1 = *(const float4*)(bnp + HH + kbase + 4);
            const float xv[8] = {x.x, x.y, x.z, x.w, y.x, y.y, y.z, y.w};
            const float scv[8] = {s0.x, s0.y, s0.z, s0.w, s1.x, s1.y, s1.z, s1.w};
            const float shv[8] = {t0.x, t0.y, t0.z, t0.w, t1.x, t1.y, t1.z, t1.w};
#pragma unroll
            for (int j = 0; j < 8; ++j)
                afrag[j] = f2bf(fmaxf(fmaf(xv[j], scv[j], shv[j]), 0.f));
        }
        const int kb = kt * 4 + q;
#pragma unroll
        for (int t = 0; t < 4; ++t)
#pragma unroll
            for (int n = 0; n < 8; ++n) {
                const bf16x8 wfrag =
                    *(const bf16x8*)(ws[t] + (size_t)kb * 1024 + (n * 16 + c16) * 8);
                acc[t][n] = __builtin_amdgcn_mfma_f32_16x16x32_bf16(wfrag, afrag, acc[t][n], 0, 0, 0);
            }
    }

    const float* const bs[4] = {b0, b1, b2, b3};
#pragma unroll
    for (int t = 0; t < 4; ++t) {
#pragma unroll
        for (int n = 0; n < 8; ++n) {
            const int col = n * 16 + q * 4;
            const float4 b4 = *(const float4*)(bs[t] + col);
            const float v[4] = {acc[t][n][0] + b4.x, acc[t][n][1] + b4.y,
                                acc[t][n][2] + b4.z, acc[t][n][3] + b4.w};
            if (t == 0) {
                *(float4*)(Ah + (size_t)row * HH + col) = make_float4(v[0], v[1], v[2], v[3]);
            } else {
                bf16x4 o;
#pragma unroll
                for (int j = 0; j < 4; ++j) o[j] = f2bf(v[j]);
                short* dstp = (t == 1) ? Bh : ((t == 2) ? Dh : Eh);
                *(bf16x4*)(dstp + (size_t)row * HH + col) = o;
            }
        }
    }
}

// Layer-1 fused edge+seg: e_new1 in regs (no store), e-BN stats, sigmoid
// seg-sum -> hnew, fused h-BN stats. Wave = 4 nodes; slot = lane>>4 (4 edge
// slots), cg = lane&15 (8 cols). Unroll-2 inner loop for gather MLP.
__global__ __launch_bounds__(256)
void edge1seg_k(const float2* __restrict__ ef_s, const int* __restrict__ src_s,
                const int* __restrict__ rowptr, const float* __restrict__ G,
                const short* __restrict__ Dh, const short* __restrict__ Eh,
                const short* __restrict__ Bh, const float* __restrict__ Ah,
                float* __restrict__ hnew, float* __restrict__ pbe,
                float* __restrict__ pbh)
{
    const int wv = threadIdx.x >> 6;
    const int lane = threadIdx.x & 63;
    const int slot = lane >> 4;
    const int cg = lane & 15;
    const int col = cg * 8;
    const int n0 = (blockIdx.x * 4 + wv) * 4;

    const float4 g00 = *(const float4*)(G + col);
    const float4 g01 = *(const float4*)(G + col + 4);
    const float4 g10 = *(const float4*)(G + HH + col);
    const float4 g11 = *(const float4*)(G + HH + col + 4);
    const float4 gb0 = *(const float4*)(G + 2 * HH + col);
    const float4 gb1 = *(const float4*)(G + 2 * HH + col + 4);
    const float G0v[8] = {g00.x, g00.y, g00.z, g00.w, g01.x, g01.y, g01.z, g01.w};
    const float G1v[8] = {g10.x, g10.y, g10.z, g10.w, g11.x, g11.y, g11.z, g11.w};
    const float GBv[8] = {gb0.x, gb0.y, gb0.z, gb0.w, gb1.x, gb1.y, gb1.z, gb1.w};

    float esa[8] = {}, esq[8] = {};
    float hsa[8] = {}, hsq[8] = {};

    for (int nn = 0; nn < 4; ++nn) {
        const int n = n0 + nn;
        const int k0 = rowptr[n], k1 = rowptr[n + 1];
        const bf16x8 ehn = *(const bf16x8*)(Eh + (size_t)n * HH + col);
        float ehv[8];
#pragma unroll
        for (int j = 0; j < 8; ++j) ehv[j] = bf2f(ehn[j]);
        float num[8] = {}, den[8] = {};
        int k = k0 + slot;
        for (; k + 4 < k1; k += 8) {
            const float2 fA = ef_s[k];
            const int sA = src_s[k];
            const float2 fB = ef_s[k + 4];
            const int sB = src_s[k + 4];
            const bf16x8 dhA = *(const bf16x8*)(Dh + (size_t)sA * HH + col);
            const bf16x8 bhA = *(const bf16x8*)(Bh + (size_t)sA * HH + col);
            const bf16x8 dhB = *(const bf16x8*)(Dh + (size_t)sB * HH + col);
            const bf16x8 bhB = *(const bf16x8*)(Bh + (size_t)sB * HH + col);
#pragma unroll
            for (int j = 0; j < 8; ++j) {
                float v = fmaf(fA.x, G0v[j], fmaf(fA.y, G1v[j], GBv[j]))
                          + bf2f(dhA[j]) + ehv[j];
                esa[j] += v; esq[j] += v * v;
                float sg = 1.f / (1.f + __expf(-v));
                den[j] += sg;
                num[j] = fmaf(sg, bf2f(bhA[j]), num[j]);
                v = fmaf(fB.x, G0v[j], fmaf(fB.y, G1v[j], GBv[j]))
                    + bf2f(dhB[j]) + ehv[j];
                esa[j] += v; esq[j] += v * v;
                sg = 1.f / (1.f + __expf(-v));
                den[j] += sg;
                num[j] = fmaf(sg, bf2f(bhB[j]), num[j]);
            }
        }
        if (k < k1) {
            const float2 fA = ef_s[k];
            const int sA = src_s[k];
            const bf16x8 dhA = *(const bf16x8*)(Dh + (size_t)sA * HH + col);
            const bf16x8 bhA = *(const bf16x8*)(Bh + (size_t)sA * HH + col);
#pragma unroll
            for (int j = 0; j < 8; ++j) {
                const float v = fmaf(fA.x, G0v[j], fmaf(fA.y, G1v[j], GBv[j]))
                                + bf2f(dhA[j]) + ehv[j];
                esa[j] += v; esq[j] += v * v;
                const float sg = 1.f / (1.f + __expf(-v));
                den[j] += sg;
                num[j] = fmaf(sg, bf2f(bhA[j]), num[j]);
            }
        }
#pragma unroll
        for (int j = 0; j < 8; ++j) {
            num[j] += __shfl_xor(num[j], 16, 64);
            den[j] += __shfl_xor(den[j], 16, 64);
            num[j] += __shfl_xor(num[j], 32, 64);
            den[j] += __shfl_xor(den[j], 32, 64);
        }
        if (slot == 0) {
            const size_t idx = (size_t)n * HH + col;
            const float4 a0 = *(const float4*)(Ah + idx);
            const float4 a1 = *(const float4*)(Ah + idx + 4);
            const float av[8] = {a0.x, a0.y, a0.z, a0.w, a1.x, a1.y, a1.z, a1.w};
            float x[8];
#pragma unroll
            for (int j = 0; j < 8; ++j) {
                x[j] = av[j] + num[j] / (den[j] + 1e-6f);
                hsa[j] += x[j]; hsq[j] += x[j] * x[j];
            }
            *(float4*)(hnew + idx) = make_float4(x[0], x[1], x[2], x[3]);
            *(float4*)(hnew + idx + 4) = make_float4(x[4], x[5], x[6], x[7]);
        }
    }

    __shared__ float sred[16][136];
    const int er = threadIdx.x >> 4;
    const int slotp = (blockIdx.x & 63) * 256;
    // pass 0: esa -> pbe[col], 1: esq -> pbe[128+col],
    // 2: hsa -> pbh[col], 3: hsq -> pbh[128+col]
#pragma unroll
    for (int pass = 0; pass < 4; ++pass) {
        const float* srcv = (pass == 0) ? esa : (pass == 1) ? esq
                           : (pass == 2) ? hsa : hsq;
        __syncthreads();
#pragma unroll
        for (int j = 0; j < 8; ++j) sred[er][col + j] = srcv[j];
        __syncthreads();
        for (int s2 = 8; s2 > 0; s2 >>= 1) {
            if (er < s2)
#pragma unroll
                for (int j = 0; j < 8; ++j) sred[er][col + j] += sred[er + s2][col + j];
            __syncthreads();
        }
        if (er == 0) {
            float* dstp = (pass < 2) ? pbe : pbh;
            const int o = (pass & 1) ? 128 : 0;
#pragma unroll
            for (int j = 0; j < 8; ++j)
                atomicAdd(dstp + slotp + o + col + j, sred[0][col + j]);
        }
    }
}

// Layer-2 edge GEMM: A = relu(bn(e_new1)) recomputed on the fly from rank-2
// map + Dh0/Eh0 gathers. 2 rows/lane; acc init = bias + Dh1[src] + Eh1[dst].
__global__ __launch_bounds__(256)
void edge2_k(const float2* __restrict__ ef_s, const float* __restrict__ Gm,
             const short* __restrict__ Dh0, const short* __restrict__ Eh0,
             const short* __restrict__ Dh1, const short* __restrict__ Eh1,
             const int* __restrict__ src_s, const int* __restrict__ dst_s,
             const short* __restrict__ Wp, const float* __restrict__ bias,
             short* __restrict__ enew)
{
    const int lane = threadIdx.x & 63;
    const int wave = threadIdx.x >> 6;
    const int q = lane >> 4;
    const int c16 = lane & 15;
    const int row0 = blockIdx.x * 128 + wave * 16 + c16;
    const int row1 = row0 + 64;

    const int s0 = src_s[row0], d0 = dst_s[row0];
    const int s1 = src_s[row1], d1 = dst_s[row1];
    const float2 ef0 = ef_s[row0];
    const float2 ef1 = ef_s[row1];

    f32x4 acc[2][8];
#pragma unroll
    for (int n = 0; n < 8; ++n) {
        const int col = n * 16 + q * 4;
        const float4 b4 = *(const float4*)(bias + col);
        const bf16x4 dh0 = *(const bf16x4*)(Dh1 + (size_t)s0 * HH + col);
        const bf16x4 eh0 = *(const bf16x4*)(Eh1 + (size_t)d0 * HH + col);
        const bf16x4 dh1 = *(const bf16x4*)(Dh1 + (size_t)s1 * HH + col);
        const bf16x4 eh1 = *(const bf16x4*)(Eh1 + (size_t)d1 * HH + col);
        const float bb[4] = {b4.x, b4.y, b4.z, b4.w};
#pragma unroll
        for (int j = 0; j < 4; ++j) {
            acc[0][n][j] = bb[j] + bf2f(dh0[j]) + bf2f(eh0[j]);
            acc[1][n][j] = bb[j] + bf2f(dh1[j]) + bf2f(eh1[j]);
        }
    }

#pragma unroll
    for (int kt = 0; kt < 4; ++kt) {
        const int kbase = kt * 32 + q * 8;
        const float4 p0 = *(const float4*)(Gm + kbase);
        const float4 p1 = *(const float4*)(Gm + kbase + 4);
        const float4 p2 = *(const float4*)(Gm + 128 + kbase);
        const float4 p3 = *(const float4*)(Gm + 128 + kbase + 4);
        const float4 p4 = *(const float4*)(Gm + 256 + kbase);
        const float4 p5 = *(const float4*)(Gm + 256 + kbase + 4);
        const float4 p6 = *(const float4*)(Gm + 384 + kbase);
        const float4 p7 = *(const float4*)(Gm + 384 + kbase + 4);
        const float g0s[8] = {p0.x, p0.y, p0.z, p0.w, p1.x, p1.y, p1.z, p1.w};
        const float g1s[8] = {p2.x, p2.y, p2.z, p2.w, p3.x, p3.y, p3.z, p3.w};
        const float gbs[8] = {p4.x, p4.y, p4.z, p4.w, p5.x, p5.y, p5.z, p5.w};
        const float scv[8] = {p6.x, p6.y, p6.z, p6.w, p7.x, p7.y, p7.z, p7.w};
        const bf16x8 dA0 = *(const bf16x8*)(Dh0 + (size_t)s0 * HH + kbase);
        const bf16x8 eA0 = *(const bf16x8*)(Eh0 + (size_t)d0 * HH + kbase);
        const bf16x8 dA1 = *(const bf16x8*)(Dh0 + (size_t)s1 * HH + kbase);
        const bf16x8 eA1 = *(const bf16x8*)(Eh0 + (size_t)d1 * HH + kbase);
        bf16x8 a0, a1;
#pragma unroll
        for (int j = 0; j < 8; ++j) {
            float t0 = fmaf(scv[j], bf2f(dA0[j]) + bf2f(eA0[j]), gbs[j]);
            t0 = fmaf(ef0.x, g0s[j], fmaf(ef0.y, g1s[j], t0));
            a0[j] = f2bf(fmaxf(t0, 0.f));
            float t1 = fmaf(scv[j], bf2f(dA1[j]) + bf2f(eA1[j]), gbs[j]);
            t1 = fmaf(ef1.x, g0s[j], fmaf(ef1.y, g1s[j], t1));
            a1[j] = f2bf(fmaxf(t1, 0.f));
        }
        const int kb = kt * 4 + q;
#pragma unroll
        for (int n = 0; n < 8; ++n) {
            const bf16x8 wfrag =
                *(const bf16x8*)(Wp + (size_t)kb * 1024 + (n * 16 + c16) * 8);
            acc[0][n] = __builtin_amdgcn_mfma_f32_16x16x32_bf16(wfrag, a0, acc[0][n], 0, 0, 0);
            acc[1][n] = __builtin_amdgcn_mfma_f32_16x16x32_bf16(wfrag, a1, acc[1][n], 0, 0, 0);
        }
    }

#pragma unroll
    for (int n = 0; n < 8; ++n) {
        const int col = n * 16 + q * 4;
        bf16x4 o0, o1;
#pragma unroll
        for (int j = 0; j < 4; ++j) {
            o0[j] = f2bf(acc[0][n][j]);
            o1[j] = f2bf(acc[1][n][j]);
        }
        *(bf16x4*)(enew + (size_t)row0 * HH + col) = o0;
        *(bf16x4*)(enew + (size_t)row1 * HH + col) = o1;
    }
}

// Vectorized per-node CSR reduction (reads e_new2) + fused h-BN stats.
// Wave = 4 nodes; unroll-2 for gather MLP.
__global__ __launch_bounds__(256)
void seg_reduce_v(const short* __restrict__ enew, const int* __restrict__ rowptr,
                  const int* __restrict__ src_s, const short* __restrict__ Bh,
                  const float* __restrict__ Ah, float* __restrict__ hnew,
                  float* __restrict__ pbuf)
{
    const int wv = threadIdx.x >> 6;
    const int lane = threadIdx.x & 63;
    const int slot = lane >> 4;
    const int cg = lane & 15;
    const int col = cg * 8;
    const int n0 = (blockIdx.x * 4 + wv) * 4;
    float sa[8] = {}, qa[8] = {};
    for (int nn = 0; nn < 4; ++nn) {
        const int n = n0 + nn;
        const int k0 = rowptr[n], k1 = rowptr[n + 1];
        float num[8] = {}, den[8] = {};
        int k = k0 + slot;
        for (; k + 4 < k1; k += 8) {
            const bf16x8 evA = *(const bf16x8*)(enew + (size_t)k * HH + col);
            const int sA = src_s[k];
            const bf16x8 evB = *(const bf16x8*)(enew + (size_t)(k + 4) * HH + col);
            const int sB = src_s[k + 4];
            const bf16x8 bvA = *(const bf16x8*)(Bh + (size_t)sA * HH + col);
            const bf16x8 bvB = *(const bf16x8*)(Bh + (size_t)sB * HH + col);
#pragma unroll
            for (int j = 0; j < 8; ++j) {
                float sg = 1.f / (1.f + __expf(-bf2f(evA[j])));
                den[j] += sg;
                num[j] = fmaf(sg, bf2f(bvA[j]), num[j]);
                sg = 1.f / (1.f + __expf(-bf2f(evB[j])));
                den[j] += sg;
                num[j] = fmaf(sg, bf2f(bvB[j]), num[j]);
            }
        }
        if (k < k1) {
            const bf16x8 ev = *(const bf16x8*)(enew + (size_t)k * HH + col);
            const int s = src_s[k];
            const bf16x8 bv = *(const bf16x8*)(Bh + (size_t)s * HH + col);
#pragma unroll
            for (int j = 0; j < 8; ++j) {
                const float sg = 1.f / (1.f + __expf(-bf2f(ev[j])));
                den[j] += sg;
                num[j] = fmaf(sg, bf2f(bv[j]), num[j]);
            }
        }
#pragma unroll
        for (int j = 0; j < 8; ++j) {
            num[j] += __shfl_xor(num[j], 16, 64);
            den[j] += __shfl_xor(den[j], 16, 64);
            num[j] += __shfl_xor(num[j], 32, 64);
            den[j] += __shfl_xor(den[j], 32, 64);
        }
        if (slot == 0) {
            const size_t idx = (size_t)n * HH + col;
            const float4 a0 = *(const float4*)(Ah + idx);
            const float4 a1 = *(const float4*)(Ah + idx + 4);
            const float av[8] = {a0.x, a0.y, a0.z, a0.w, a1.x, a1.y, a1.z, a1.w};
            float x[8];
#pragma unroll
            for (int j = 0; j < 8; ++j) {
                x[j] = av[j] + num[j] / (den[j] + 1e-6f);
                sa[j] += x[j]; qa[j] += x[j] * x[j];
            }
            *(float4*)(hnew + idx) = make_float4(x[0], x[1], x[2], x[3]);
            *(float4*)(hnew + idx + 4) = make_float4(x[4], x[5], x[6], x[7]);
        }
    }
    if (slot == 0) {
        const int sl = (blockIdx.x & 63) * 256;
#pragma unroll
        for (int j = 0; j < 8; ++j) {
            atomicAdd(pbuf + sl + col + j, sa[j]);
            atomicAdd(pbuf + sl + 128 + col + j, qa[j]);
        }
    }
}

// Fused readout: logits = relu(relu(bn(hnew)) @ w1 + b1) @ w2 + b2.
__global__ __launch_bounds__(256)
void readout_k(const float* __restrict__ hnew, const float* __restrict__ bnp,
               const short* __restrict__ Wp, const float* __restrict__ b1,
               const float* __restrict__ w2, const float* __restrict__ b2,
               float* __restrict__ out)
{
    const int lane = threadIdx.x & 63;
    const int wave = threadIdx.x >> 6;
    const int q = lane >> 4;
    const int c16 = lane & 15;
    const int row = blockIdx.x * 64 + wave * 16 + c16;

    f32x4 acc[8];
#pragma unroll
    for (int n = 0; n < 8; ++n) acc[n] = (f32x4){0.f, 0.f, 0.f, 0.f};

#pragma unroll
    for (int kt = 0; kt < 4; ++kt) {
        const int kbase = kt * 32 + q * 8;
        const float* p = hnew + (size_t)row * HH + kbase;
        const float4 x = *(const float4*)p;
        const float4 y = *(const float4*)(p + 4);
        const float4 s0 = *(const float4*)(bnp + kbase);
        const float4 s1 = *(const float4*)(bnp + kbase + 4);
        const float4 t0 = *(const float4*)(bnp + HH + kbase);
        const float4 t1 = *(const float4*)(bnp + HH + kbase + 4);
        const float xv[8] = {x.x, x.y, x.z, x.w, y.x, y.y, y.z, y.w};
        const float scv[8] = {s0.x, s0.y, s0.z, s0.w, s1.x, s1.y, s1.z, s1.w};
        const float shv[8] = {t0.x, t0.y, t0.z, t0.w, t1.x, t1.y, t1.z, t1.w};
        bf16x8 afrag;
#pragma unroll
        for (int j = 0; j < 8; ++j)
            afrag[j] = f2bf(fmaxf(fmaf(xv[j], scv[j], shv[j]), 0.f));
        const int kb = kt * 4 + q;
#pragma unroll
        for (int n = 0; n < 8; ++n) {
            const bf16x8 wfrag =
                *(const bf16x8*)(Wp + (size_t)kb * 1024 + (n * 16 + c16) * 8);
            acc[n] = __builtin_amdgcn_mfma_f32_16x16x32_bf16(wfrag, afrag, acc[n], 0, 0, 0);
        }
    }

    float part[NCLS] = {};
#pragma unroll
    for (int n = 0; n < 8; ++n) {
        const int col = n * 16 + q * 4;
        const float4 b4 = *(const float4*)(b1 + col);
        const float bb[4] = {b4.x, b4.y, b4.z, b4.w};
#pragma unroll
        for (int j = 0; j < 4; ++j) {
            const float zv = fmaxf(acc[n][j] + bb[j], 0.f);
#pragma unroll
            for (int t = 0; t < NCLS; ++t)
                part[t] = fmaf(zv, w2[(col + j) * NCLS + t], part[t]);
        }
    }
#pragma unroll
    for (int t = 0; t < NCLS; ++t) {
        part[t] += __shfl_xor(part[t], 16, 64);
        part[t] += __shfl_xor(part[t], 32, 64);
    }
    if (q == 0) {
#pragma unroll
        for (int t = 0; t < NCLS; ++t)
            out[(size_t)row * NCLS + t] = part[t] + b2[t];
    }
}

// Pack all weight matrices to bf16 fragments: Wp[kb][col][8] = W[kb*8+j][col].
__global__ __launch_bounds__(256)
void prepack_k(const float* __restrict__ enc_nw, const float* __restrict__ lin_w,
               const float* __restrict__ mlp_w1, short* __restrict__ wp)
{
    const int t = blockIdx.x * 256 + threadIdx.x;
    if (t >= 260 * 128) return;
    const int kbg = t >> 7, col = t & 127;
    const int kb0[11]  = {0, 100, 116, 132, 148, 164, 180, 196, 212, 228, 244};
    const int psel[11] = {0, 1, 1, 1, 1, 1, 1, 1, 1, 1, 2};
    const int soff[11] = {0, 0 * 16384, 1 * 16384, 3 * 16384, 4 * 16384,
                          5 * 16384, 6 * 16384, 7 * 16384, 8 * 16384, 9 * 16384, 0};
    const int Ksrc[11] = {KIN, 128, 128, 128, 128, 128, 128, 128, 128, 128, 128};
    int e = 10;
    while (e > 0 && kbg < kb0[e]) --e;
    const float* base = (psel[e] == 0) ? enc_nw : ((psel[e] == 1) ? lin_w : mlp_w1);
    const int kbl = kbg - kb0[e];
    bf16x8 o;
#pragma unroll
    for (int j = 0; j < 8; ++j) {
        const int k = kbl * 8 + j;
        const float v = (k < Ksrc[e]) ? base[(size_t)soff[e] + (size_t)k * HH + col] : 0.f;
        o[j] = f2bf(v);
    }
    *(bf16x8*)(wp + (size_t)kbg * 1024 + col * 8) = o;
}

// Rank-2 collapse of layer-1 edge GEMM.
__global__ void gpre_k(const float* __restrict__ enc_ew, const float* __restrict__ enc_eb,
                       const float* __restrict__ Wc, const float* __restrict__ bc,
                       float* __restrict__ G)
{
    const int c = threadIdx.x;
    float a0 = 0.f, a1 = 0.f, ab = 0.f;
    for (int k = 0; k < HH; ++k) {
        const float w = Wc[k * HH + c];
        a0 = fmaf(enc_ew[k], w, a0);
        a1 = fmaf(enc_ew[HH + k], w, a1);
        ab = fmaf(enc_eb[k], w, ab);
    }
    G[c] = a0; G[HH + c] = a1; G[2 * HH + c] = ab + bc[c];
}

// ---- CSR build ----
__global__ __launch_bounds__(256)
void hist_k(const int* __restrict__ dst, int* __restrict__ cnt)
{
    const int e = blockIdx.x * 256 + threadIdx.x;
    if (e < NE) atomicAdd(cnt + dst[e], 1);
}

__global__ __launch_bounds__(1024)
void scan_k(const int* __restrict__ cnt, int* __restrict__ rowptr, int* __restrict__ wr)
{
    __shared__ int s[1024];
    const int t = threadIdx.x;
    const int base = t * 40;
    int sum = 0;
    for (int i = 0; i < 40; ++i) {
        const int idx = base + i;
        if (idx < NN) sum += cnt[idx];
    }
    s[t] = sum;
    __syncthreads();
    for (int off = 1; off < 1024; off <<= 1) {
        const int v = (t >= off) ? s[t - off] : 0;
        __syncthreads();
        s[t] += v;
        __syncthreads();
    }
    int run = (t == 0) ? 0 : s[t - 1];
    for (int i = 0; i < 40; ++i) {
        const int idx = base + i;
        if (idx < NN) {
            rowptr[idx] = run;
            wr[idx] = run;
            run += cnt[idx];
        }
    }
    if (t == 1023) rowptr[NN] = s[1023];
}

// Scatter edges to dst-sorted order; pre-gather edge_feat into ef_s.
__global__ __launch_bounds__(256)
void scatter_k(const int* __restrict__ dst, const int* __restrict__ src,
               const float* __restrict__ ef, int* __restrict__ wr,
               int* __restrict__ src_s, int* __restrict__ dst_s,
               float2* __restrict__ ef_s)
{
    const int e = blockIdx.x * 256 + threadIdx.x;
    if (e < NE) {
        const int d = dst[e];
        const int p = atomicAdd(wr + d, 1);
        src_s[p] = src[e];
        dst_s[p] = d;
        ef_s[p] = ((const float2*)ef)[e];
    }
}

// BN params from 64-slot partials; optionally also fold into the rank-2 map.
template<bool DOGM>
__global__ void make_bnp2(const float* __restrict__ pbuf, const float* __restrict__ g,
                          const float* __restrict__ b, float cntInv,
                          float* __restrict__ out, const float* __restrict__ G,
                          float* __restrict__ Gm)
{
    const int c = threadIdx.x;
    float s = 0.f, q = 0.f;
    for (int i = 0; i < 64; ++i) {
        s += pbuf[i * 256 + c];
        q += pbuf[i * 256 + 128 + c];
    }
    const float m = s * cntInv;
    const float var = q * cntInv - m * m;
    const float rs = rsqrtf(var + 1e-5f);
    const float sc = g[c] * rs;
    const float sh = b[c] - m * sc;
    out[c] = sc;
    out[128 + c] = sh;
    if (DOGM) {
        Gm[c] = G[c] * sc;
        Gm[128 + c] = G[HH + c] * sc;
        Gm[256 + c] = fmaf(G[2 * HH + c], sc, sh);
        Gm[384 + c] = sc;
    }
}

extern "C" void kernel_launch(void* const* d_in, const int* in_sizes, int n_in,
                              void* d_out, int out_size, void* d_ws, size_t ws_size,
                              hipStream_t stream)
{
    const float* node_feat = (const float*)d_in[0];
    const float* edge_feat = (const float*)d_in[1];
    const int*   src       = (const int*)d_in[2];
    const int*   dst       = (const int*)d_in[3];
    const float* enc_nw    = (const float*)d_in[4];
    const float* enc_nb    = (const float*)d_in[5];
    const float* enc_ew    = (const float*)d_in[6];
    const float* enc_eb    = (const float*)d_in[7];
    const float* lin_w     = (const float*)d_in[8];
    const float* lin_b     = (const float*)d_in[9];
    const float* bnh_g     = (const float*)d_in[10];
    const float* bnh_b     = (const float*)d_in[11];
    const float* bne_g     = (const float*)d_in[12];
    const float* bne_b     = (const float*)d_in[13];
    const float* mlp_w1    = (const float*)d_in[14];
    const float* mlp_b1    = (const float*)d_in[15];
    const float* mlp_w2    = (const float*)d_in[16];
    const float* mlp_b2    = (const float*)d_in[17];
    float* out = (float*)d_out;

    char* base = (char*)d_ws;
    size_t off = 0;
    auto alloc = [&](size_t bytes) -> void* {
        void* p = base + off;
        off = (off + bytes + 255) & ~(size_t)255;
        return p;
    };
    const size_t NH = (size_t)NN * HH;
    float* hnew  = (float*)alloc(NH * 4);
    float* Ah    = (float*)alloc(NH * 4);
    short* h0    = (short*)alloc(NH * 2);     // encoder out; reused as Bh1
    short* Bh0   = (short*)alloc(NH * 2);
    short* Dh0   = (short*)alloc(NH * 2);
    short* Eh0   = (short*)alloc(NH * 2);
    short* Dh1   = (short*)alloc(NH * 2);
    short* Eh1   = (short*)alloc(NH * 2);
    short* enew  = (short*)alloc((size_t)NE * HH * 2);   // e_new2 only
    short* wpack = (short*)alloc((size_t)260 * 1024 * 2);
    float* G     = (float*)alloc(384 * 4);
    float* Gm    = (float*)alloc(512 * 4);
    float* bnpe  = (float*)alloc(256 * 4);
    float* bnph  = (float*)alloc(256 * 4);
    float* pbe   = (float*)alloc(16384 * 4);
    float* pbh0  = (float*)alloc(16384 * 4);
    float* pbh1  = (float*)alloc(16384 * 4);
    int* cnt     = (int*)alloc(NN * 4);
    int* rowptr  = (int*)alloc((NN + 1) * 4);
    int* wr      = (int*)alloc(NN * 4);
    int* src_s   = (int*)alloc((size_t)NE * 4);
    int* dst_s   = (int*)alloc((size_t)NE * 4);
    float2* ef_s = (float2*)alloc((size_t)NE * 8);

    const dim3 blk(256);

    hipMemsetAsync(cnt, 0, NN * 4, stream);
    hipMemsetAsync(pbe, 0, 3 * 16384 * 4, stream);   // pbe,pbh0,pbh1 contiguous
    hist_k<<<2500, blk, 0, stream>>>(dst, cnt);
    scan_k<<<1, 1024, 0, stream>>>(cnt, rowptr, wr);
    scatter_k<<<2500, blk, 0, stream>>>(dst, src, edge_feat, wr, src_s, dst_s, ef_s);
    prepack_k<<<130, blk, 0, stream>>>(enc_nw, lin_w, mlp_w1, wpack);
    gpre_k<<<1, 128, 0, stream>>>(enc_ew, enc_eb, lin_w + 2 * 16384, lin_b + 2 * HH, G);

    // encoder: h0 = bf16(node_feat @ enc_nw + enc_nb)
    mfma_gemm<25, true><<<625, blk, 0, stream>>>(node_feat, wpack, enc_nb, h0, KIN);

    // ---- layer 0 ----
    {
        const float* Bv = lin_b;
        fused4_k<false><<<625, blk, 0, stream>>>(
            h0, nullptr, nullptr,
            wpack + (size_t)100 * 1024, wpack + (size_t)116 * 1024,
            wpack + (size_t)132 * 1024, wpack + (size_t)148 * 1024,
            Bv + 0 * HH, Bv + 1 * HH, Bv + 3 * HH, Bv + 4 * HH,
            Ah, Bh0, Dh0, Eh0);
        edge1seg_k<<<2500, blk, 0, stream>>>(ef_s, src_s, rowptr, G,
                                             Dh0, Eh0, Bh0, Ah, hnew, pbe, pbh0);
        make_bnp2<true><<<1, 128, 0, stream>>>(pbe, bne_g, bne_b, 1.f / NE, bnpe, G, Gm);
        make_bnp2<false><<<1, 128, 0, stream>>>(pbh0, bnh_g, bnh_b, 1.f / NN, bnph,
                                                nullptr, nullptr);
    }

    // ---- layer 1 ----
    {
        const float* Bv = lin_b + 5 * HH;
        short* Bh1 = h0;   // h0 dead after layer-0 fused4
        fused4_k<true><<<625, blk, 0, stream>>>(
            nullptr, hnew, bnph,
            wpack + (size_t)164 * 1024, wpack + (size_t)180 * 1024,
            wpack + (size_t)212 * 1024, wpack + (size_t)228 * 1024,
            Bv + 0 * HH, Bv + 1 * HH, Bv + 3 * HH, Bv + 4 * HH,
            Ah, Bh1, Dh1, Eh1);
        edge2_k<<<5000, blk, 0, stream>>>(ef_s, Gm, Dh0, Eh0, Dh1, Eh1,
                                          src_s, dst_s, wpack + (size_t)196 * 1024,
                                          Bv + 2 * HH, enew);
        seg_reduce_v<<<2500, blk, 0, stream>>>(enew, rowptr, src_s, Bh1, Ah, hnew, pbh1);
        make_bnp2<false><<<1, 128, 0, stream>>>(pbh1, bnh_g + HH, bnh_b + HH, 1.f / NN,
                                                bnph, nullptr, nullptr);
    }

    // fused readout
    readout_k<<<625, blk, 0, stream>>>(hnew, bnph, wpack + (size_t)244 * 1024,
                                       mlp_b1, mlp_w2, mlp_b2, out);
}